// Round 12
// baseline (256.998 us; speedup 1.0000x reference)
//
#include <hip/hip_runtime.h>
#include <hip/hip_bf16.h>

#define B_ 4
#define C_ 256
#define N_ 4096
#define BN_ (B_*N_)

typedef float f32x4 __attribute__((ext_vector_type(4)));
typedef short bf16x8 __attribute__((ext_vector_type(8)));
typedef short short4v __attribute__((ext_vector_type(4)));
typedef int   int4v  __attribute__((ext_vector_type(4)));

static __device__ __forceinline__ short f2bf(float f){
  unsigned u = __builtin_bit_cast(unsigned, f);
  u += 0x7FFFu + ((u >> 16) & 1u);
  return (short)(u >> 16);
}
static __device__ __forceinline__ float bf2f(short s){
  unsigned u = ((unsigned)(unsigned short)s) << 16;
  return __builtin_bit_cast(float, u);
}
static __device__ __forceinline__ int cvtpk(float lo, float hi){
  int r;
  asm("v_cvt_pk_bf16_f32 %0, %1, %2" : "=v"(r) : "v"(lo), "v"(hi));
  return r;
}
static __device__ __forceinline__ void gload_lds16(const void* g, void* l){
  __builtin_amdgcn_global_load_lds((const __attribute__((address_space(1))) unsigned*)g,
                                   (__attribute__((address_space(3))) unsigned*)l, 16, 0, 0);
}

// ---------------- K1: feat = mean + max over (h,w) ----------------
__global__ __launch_bounds__(256) void k_feat(const float* __restrict__ x, float* __restrict__ feat){
  int row = blockIdx.x; // b*C + c
  const f32x4* p = (const f32x4*)(x + (size_t)row * N_);
  float s = 0.f, mx = -1e30f;
  for (int i = threadIdx.x; i < N_/4; i += 256){
    f32x4 v = p[i];
    s += v.x + v.y + v.z + v.w;
    mx = fmaxf(mx, fmaxf(fmaxf(v.x, v.y), fmaxf(v.z, v.w)));
  }
  __shared__ float ss[256];
  __shared__ float sm[256];
  int t = threadIdx.x;
  ss[t] = s; sm[t] = mx;
  __syncthreads();
  for (int off = 128; off > 0; off >>= 1){
    if (t < off){ ss[t] += ss[t+off]; sm[t] = fmaxf(sm[t], sm[t+off]); }
    __syncthreads();
  }
  if (t == 0) feat[row] = ss[0] * (1.f/(float)N_) + sm[0];
}

// ---------------- K2: complexity gate ----------------
__global__ __launch_bounds__(64) void k_cplx(const float* __restrict__ feat, const float* __restrict__ w1,
    const float* __restrict__ w2, float* __restrict__ cplx){
  int b = blockIdx.x, l = threadIdx.x;
  float contrib = 0.f;
  if (l < 32){
    const float* wr = w1 + l*C_;
    const float* f = feat + b*C_;
    float d = 0.f;
    for (int c = 0; c < C_; c++) d += wr[c]*f[c];
    float sg = 1.f/(1.f + expf(-d));
    contrib = (d*sg)*w2[l];
  }
  #pragma unroll
  for (int off = 1; off < 64; off <<= 1) contrib += __shfl_xor(contrib, off);
  if (l == 0) cplx[b] = 1.f/(1.f + expf(-contrib));
}

// ---------------- K2b: convert weights to bf16 ----------------
__global__ __launch_bounds__(256) void k_wcvt(const float* __restrict__ a, const float* __restrict__ b,
    const float* __restrict__ c, const float* __restrict__ d,
    short* __restrict__ oa, short* __restrict__ ob2, short* __restrict__ oc, short* __restrict__ od){
  int m = blockIdx.x >> 6;
  int off = (blockIdx.x & 63)*1024 + threadIdx.x*4;
  const float* src = (m==0)?a:(m==1)?b:(m==2)?c:d;
  short* dst = (m==0)?oa:(m==1)?ob2:(m==2)?oc:od;
  f32x4 v = *(const f32x4*)(src + off);
  short4v s;
  #pragma unroll
  for (int j = 0; j < 4; j++) s[j] = f2bf(v[j]);
  *(short4v*)(dst + off) = s;
}

// ---------------- K3: fused QKV projection v2 ----------------
// Grid (256 n-blocks, 4 b): each block owns a distinct 16-row n-slice of x
// (16 KB, read from HBM exactly once), o-loop inside: wave w covers
// o in [w*64, w*64+64). Weights stream from L2 (512 KB resident).
__global__ __launch_bounds__(256) void k_qkv(const float* __restrict__ x,
    const short* __restrict__ wqb, const short* __restrict__ wkb, const short* __restrict__ wvb,
    short* __restrict__ Q, short* __restrict__ K, short* __restrict__ Vt){
  int b = blockIdx.y, n0 = blockIdx.x*16;
  int tid = threadIdx.x, w = tid>>6, l = tid&63, lq = l&15, lg = l>>4;
  const float* xb = x + (size_t)b*C_*N_;
  int nrow = n0 + lq;

  // A fragments (shared n-tile): 8 kk x 8 elems, 32 VGPR, held across o-loop
  bf16x8 a[8];
  #pragma unroll
  for (int kk = 0; kk < 8; kk++){
    int c0 = kk*32 + lg*8;
    #pragma unroll
    for (int j = 0; j < 8; j++) a[kk][j] = f2bf(xb[(size_t)(c0+j)*N_ + nrow]);
  }

  f32x4 zero = {0.f,0.f,0.f,0.f};
  f32x4 acc[3][4];
  #pragma unroll
  for (int m = 0; m < 3; m++)
    #pragma unroll
    for (int s = 0; s < 4; s++) acc[m][s] = zero;

  for (int kk = 0; kk < 8; ++kk){
    #pragma unroll
    for (int s = 0; s < 4; s++){
      int base = (w*64 + s*16 + lq)*C_ + kk*32 + lg*8;
      bf16x8 aq = *(const bf16x8*)(wqb + base);
      bf16x8 ak = *(const bf16x8*)(wkb + base);
      bf16x8 av = *(const bf16x8*)(wvb + base);
      acc[0][s] = __builtin_amdgcn_mfma_f32_16x16x32_bf16(a[kk], aq, acc[0][s], 0, 0, 0);
      acc[1][s] = __builtin_amdgcn_mfma_f32_16x16x32_bf16(a[kk], ak, acc[1][s], 0, 0, 0);
      acc[2][s] = __builtin_amdgcn_mfma_f32_16x16x32_bf16(a[kk], av, acc[2][s], 0, 0, 0);
    }
  }
  // Q/K store: n = n0 + lg*4 + r, o = w*64 + s*16 + lq
  #pragma unroll
  for (int s = 0; s < 4; s++)
    #pragma unroll
    for (int r = 0; r < 4; r++){
      int n = n0 + lg*4 + r;
      int o = w*64 + s*16 + lq;
      size_t idx = ((size_t)b*N_ + n)*C_ + o;
      Q[idx] = f2bf(acc[0][s][r] * 0.0625f);
      K[idx] = f2bf(acc[1][s][r]);
    }
  // V transpose through LDS: lv[o][n-local], padded stride 18
  __shared__ short lv[256][18];
  #pragma unroll
  for (int s = 0; s < 4; s++)
    #pragma unroll
    for (int r = 0; r < 4; r++)
      lv[w*64 + s*16 + lq][lg*4 + r] = f2bf(acc[2][s][r]);
  __syncthreads();
  {
    int o = tid;
    short* dst = Vt + ((size_t)b*C_ + o)*N_ + n0;
    #pragma unroll
    for (int q = 0; q < 4; q++){
      short4v v;
      #pragma unroll
      for (int j = 0; j < 4; j++) v[j] = lv[o][q*4 + j];
      *(short4v*)(dst + q*4) = v;
    }
  }
}

// ---------------- K4: flash attention v8 (R8 verbatim - proven 91 us) ----------------
__global__ __launch_bounds__(512, 2) void k_attn4(const short* __restrict__ Q, const short* __restrict__ K,
    const short* __restrict__ Vt, short* __restrict__ Op, float* __restrict__ Mp, float* __restrict__ Lp){
  extern __shared__ short smem[];   // Ks[2][32][256] | Vs[2][256][32]
  short* KsBase = smem;             // 2*8192 shorts
  short* VsBase = smem + 16384;     // 2*8192 shorts

  int bid = blockIdx.x;
  int xcd = bid & 7, idx = bid >> 3;
  int b = xcd >> 1;
  int part = ((xcd & 1) << 1) | (idx & 1);
  int n0 = (idx >> 1) * 256;
  int kv0 = part * 1024;
  int tid = threadIdx.x, w = tid>>6, l = tid&63, lq = l&15, lg = l>>4;
  const short* Qb = Q + (size_t)b*N_*C_;
  const short* Kb = K + (size_t)b*N_*C_;
  const short* Vb = Vt + (size_t)b*C_*N_;

  // staging lane constants (chunk id = w*128 + i*64 + l, i in {0,1})
  int cid0 = w*128 + l;
  auto stage = [&](int buf, int m0){
    short* kd = KsBase + buf*8192 + w*1024;
    short* vd = VsBase + buf*8192 + w*1024;
    #pragma unroll
    for (int i = 0; i < 2; i++){
      int cid = cid0 + i*64;
      int krow = cid >> 5;                       // 0..31
      int kch  = (cid & 31) ^ (krow & 7);
      gload_lds16(Kb + (size_t)(m0 + krow)*C_ + kch*8, kd + i*512);
      int vrow = cid >> 2;                       // 0..255
      int vch  = (cid & 3) ^ (vrow & 3);
      gload_lds16(Vb + (size_t)vrow*N_ + m0 + vch*8, vd + i*512);
    }
  };

  // Q fragments hoisted: 2 q-tiles x 8 kk  (64 VGPR)
  bf16x8 qf[2][8];
  #pragma unroll
  for (int qt = 0; qt < 2; qt++){
    const short* qrow = Qb + (size_t)(n0 + w*32 + qt*16 + lq)*C_ + lg*8;
    #pragma unroll
    for (int kk = 0; kk < 8; kk++) qf[qt][kk] = *(const bf16x8*)(qrow + kk*32);
  }

  f32x4 zero = {0.f,0.f,0.f,0.f};
  f32x4 oacc[2][16];                 // 128 VGPR
  #pragma unroll
  for (int qt = 0; qt < 2; qt++)
    #pragma unroll
    for (int c = 0; c < 16; c++) oacc[qt][c] = zero;
  float m[2] = {-1e30f, -1e30f}, lsum[2] = {0.f, 0.f};
  int swz = lq & 7;
  int a01 = ((2*(lg & 1))*16 + lq) * 4;
  int a23 = a01 + 64;
  bool hiHalf = (l >= 32);

  stage(0, kv0);
  __syncthreads();
  int cur = 0;

  for (int mt = 0; mt < 32; mt++){
    if (mt + 1 < 32) stage(cur^1, kv0 + (mt+1)*32);
    const short* Kc = KsBase + cur*8192;
    const short* Vc = VsBase + cur*8192;

    // ---- QK^T: sa[qt][s] cols = q (lane&15), rows = k = s*16 + 4*lg + r
    f32x4 sa[2][2];
    #pragma unroll
    for (int qt = 0; qt < 2; qt++){ sa[qt][0] = zero; sa[qt][1] = zero; }
    __builtin_amdgcn_s_setprio(1);
    #pragma unroll
    for (int s = 0; s < 2; s++){
      const short* krowp = Kc + (s*16 + lq)*256;
      #pragma unroll
      for (int kk = 0; kk < 8; kk++){
        bf16x8 kf = *(const bf16x8*)(krowp + (((kk*4 + lg) ^ swz) << 3));
        sa[0][s] = __builtin_amdgcn_mfma_f32_16x16x32_bf16(kf, qf[0][kk], sa[0][s], 0, 0, 0);
        sa[1][s] = __builtin_amdgcn_mfma_f32_16x16x32_bf16(kf, qf[1][kk], sa[1][s], 0, 0, 0);
      }
    }
    __builtin_amdgcn_s_setprio(0);

    // ---- softmax per q-tile (per-lane scalar state, q = lane&15)
    int W[2][2][2];
    #pragma unroll
    for (int qt = 0; qt < 2; qt++){
      float pmax = sa[qt][0][0];
      #pragma unroll
      for (int s = 0; s < 2; s++)
        #pragma unroll
        for (int r = 0; r < 4; r++) pmax = fmaxf(pmax, sa[qt][s][r]);
      pmax = fmaxf(pmax, __shfl_xor(pmax, 16));
      pmax = fmaxf(pmax, __shfl_xor(pmax, 32));
      if (__any(pmax > m[qt] + 8.f)){
        float mn = fmaxf(m[qt], pmax);
        float al = __expf(m[qt] - mn);
        m[qt] = mn;
        lsum[qt] *= al;
        float alo[4];
        #pragma unroll
        for (int r = 0; r < 4; r++) alo[r] = __shfl(al, (l & 48) | (lg*4 + r));
        #pragma unroll
        for (int c = 0; c < 16; c++){
          f32x4 o = oacc[qt][c];
          o[0]*=alo[0]; o[1]*=alo[1]; o[2]*=alo[2]; o[3]*=alo[3];
          oacc[qt][c] = o;
        }
      }
      #pragma unroll
      for (int s = 0; s < 2; s++)
        #pragma unroll
        for (int r = 0; r < 4; r++) sa[qt][s][r] = __expf(sa[qt][s][r] - m[qt]);
      float ts = 0.f;
      #pragma unroll
      for (int s = 0; s < 2; s++) ts += sa[qt][s][0] + sa[qt][s][1] + sa[qt][s][2] + sa[qt][s][3];
      ts += __shfl_xor(ts, 16);
      ts += __shfl_xor(ts, 32);
      lsum[qt] += ts;
      #pragma unroll
      for (int s = 0; s < 2; s++){
        W[qt][s][0] = cvtpk(sa[qt][s][0], sa[qt][s][1]);
        W[qt][s][1] = cvtpk(sa[qt][s][2], sa[qt][s][3]);
      }
    }

    // ---- P repack to A-frag via bpermute (per q-tile)
    bf16x8 pa[2];
    #pragma unroll
    for (int qt = 0; qt < 2; qt++){
      int lo0 = __builtin_amdgcn_ds_bpermute(a01, W[qt][0][0]);
      int hi0 = __builtin_amdgcn_ds_bpermute(a01, W[qt][1][0]);
      int lo1 = __builtin_amdgcn_ds_bpermute(a01, W[qt][0][1]);
      int hi1 = __builtin_amdgcn_ds_bpermute(a01, W[qt][1][1]);
      int lo2 = __builtin_amdgcn_ds_bpermute(a23, W[qt][0][0]);
      int hi2 = __builtin_amdgcn_ds_bpermute(a23, W[qt][1][0]);
      int lo3 = __builtin_amdgcn_ds_bpermute(a23, W[qt][0][1]);
      int hi3 = __builtin_amdgcn_ds_bpermute(a23, W[qt][1][1]);
      int4v pw;
      pw[0] = hiHalf ? hi0 : lo0;
      pw[1] = hiHalf ? hi1 : lo1;
      pw[2] = hiHalf ? hi2 : lo2;
      pw[3] = hiHalf ? hi3 : lo3;
      pa[qt] = __builtin_bit_cast(bf16x8, pw);
    }

    // ---- PV: V B-frag from LDS, shared across both q-tiles
    __builtin_amdgcn_s_setprio(1);
    #pragma unroll
    for (int c = 0; c < 16; c++){
      int vr = c*16 + lq;
      bf16x8 vbf = *(const bf16x8*)(Vc + vr*32 + ((lg ^ (vr & 3)) << 3));
      oacc[0][c] = __builtin_amdgcn_mfma_f32_16x16x32_bf16(pa[0], vbf, oacc[0][c], 0, 0, 0);
      oacc[1][c] = __builtin_amdgcn_mfma_f32_16x16x32_bf16(pa[1], vbf, oacc[1][c], 0, 0, 0);
    }
    __builtin_amdgcn_s_setprio(0);

    __syncthreads();   // readers done with buf cur; staged loads for cur^1 drained
    cur ^= 1;
  }

  #pragma unroll
  for (int qt = 0; qt < 2; qt++){
    float inv = 1.f / lsum[qt];
    float invo[4];
    #pragma unroll
    for (int r = 0; r < 4; r++) invo[r] = __shfl(inv, (l & 48) | (lg*4 + r));
    #pragma unroll
    for (int c = 0; c < 16; c++)
      #pragma unroll
      for (int r = 0; r < 4; r++){
        int n = n0 + w*32 + qt*16 + lg*4 + r;
        Op[((size_t)part*BN_ + (size_t)b*N_ + n)*C_ + c*16 + lq] = f2bf(oacc[qt][c][r]*invo[r]);
      }
    if (lg == 0){
      int n = n0 + w*32 + qt*16 + lq;
      Mp[part*BN_ + b*N_ + n] = m[qt];
      Lp[part*BN_ + b*N_ + n] = lsum[qt];
    }
  }
}

// ---------------- K4b: combine 4 KV quarters ----------------
__global__ __launch_bounds__(256) void k_comb4(const short* __restrict__ Op, const float* __restrict__ Mp,
    const float* __restrict__ Lp, short* __restrict__ Xa){
  int tid = threadIdx.x;
  int rg = blockIdx.x*8 + (tid>>5);
  int cc = (tid&31)*8;
  float mv[4], lv[4];
  float m = -1e30f;
  #pragma unroll
  for (int p = 0; p < 4; p++){ mv[p] = Mp[p*BN_ + rg]; lv[p] = Lp[p*BN_ + rg]; m = fmaxf(m, mv[p]); }
  float wgt[4], wsum = 0.f;
  #pragma unroll
  for (int p = 0; p < 4; p++){ wgt[p] = lv[p]*__expf(mv[p]-m); wsum += wgt[p]; }
  float inv = 1.f/wsum;
  float acc[8];
  #pragma unroll
  for (int j = 0; j < 8; j++) acc[j] = 0.f;
  #pragma unroll
  for (int p = 0; p < 4; p++){
    bf16x8 o = *(const bf16x8*)(Op + ((size_t)p*BN_ + rg)*C_ + cc);
    #pragma unroll
    for (int j = 0; j < 8; j++) acc[j] += wgt[p]*bf2f(o[j]);
  }
  bf16x8 r;
  #pragma unroll
  for (int j = 0; j < 8; j++) r[j] = f2bf(acc[j]*inv);
  *(bf16x8*)(Xa + (size_t)rg*C_ + cc) = r;
}

// ---------------- K4 fallback (R4-proven): 2-way split, dbuf K+V in LDS ----------------
__global__ __launch_bounds__(512) void k_attn2(const short* __restrict__ Q, const short* __restrict__ K,
    const short* __restrict__ Vt, short* __restrict__ Op, float* __restrict__ Mp, float* __restrict__ Lp){
  extern __shared__ short smem[];
  short* Ks = smem;
  short* Vs = smem + 32768;
  int bid = blockIdx.x;
  int xcd = bid & 7;
  int b = xcd >> 1;
  int half = xcd & 1;
  int n0 = (bid >> 3) * 128;
  int kv0 = half * 2048;
  int tid = threadIdx.x, w = tid>>6, l = tid&63, lq = l&15, lg = l>>4;
  const short* Qb = Q + (size_t)b*N_*C_;
  const short* Kb = K + (size_t)b*N_*C_;
  const short* Vb = Vt + (size_t)b*C_*N_;
  short* lp = smem + 65536 + w*(16*72);
  int krow0 = w*8 + (l>>5);
  int kchunk0 = l&31;
  int vrow0 = w*32 + (l>>3);
  int vchunk = (l&7) ^ ((l>>3)&7);
  bf16x8 qf[8];
  {
    const short* qrow = Qb + (size_t)(n0 + w*16 + lq)*C_ + lg*8;
    #pragma unroll
    for (int kk = 0; kk < 8; kk++) qf[kk] = *(const bf16x8*)(qrow + kk*32);
  }
  f32x4 zero = {0.f,0.f,0.f,0.f};
  f32x4 oacc[16];
  #pragma unroll
  for (int c = 0; c < 16; c++) oacc[c] = zero;
  float mrow[4], lsum[4];
  #pragma unroll
  for (int r = 0; r < 4; r++){ mrow[r] = -1e30f; lsum[r] = 0.f; }
  int swz = lq & 7;
  auto stage = [&](int buf, int m0){
    short* kd = Ks + buf*16384 + w*2048;
    short* vd = Vs + buf*16384 + w*2048;
    #pragma unroll
    for (int i = 0; i < 4; i++){
      int row = krow0 + i*2;
      int chunk = kchunk0 ^ (row & 7);
      gload_lds16(Kb + (size_t)(m0 + row)*C_ + chunk*8, kd + i*512);
    }
    #pragma unroll
    for (int i = 0; i < 4; i++){
      int row = vrow0 + i*8;
      gload_lds16(Vb + (size_t)row*N_ + m0 + vchunk*8, vd + i*512);
    }
  };
  stage(0, kv0);
  __syncthreads();
  int cur = 0;
  for (int mt = 0; mt < 32; mt++){
    if (mt + 1 < 32) stage(cur^1, kv0 + (mt+1)*64);
    const short* Kc = Ks + cur*16384;
    const short* Vc = Vs + cur*16384;
    f32x4 sa[4];
    #pragma unroll
    for (int s = 0; s < 4; s++) sa[s] = zero;
    __builtin_amdgcn_s_setprio(1);
    #pragma unroll
    for (int s = 0; s < 4; s++){
      const short* krowp = Kc + (s*16 + lq)*256;
      #pragma unroll
      for (int kk = 0; kk < 8; kk++){
        bf16x8 kf = *(const bf16x8*)(krowp + (((kk*4 + lg) ^ swz) << 3));
        sa[s] = __builtin_amdgcn_mfma_f32_16x16x32_bf16(qf[kk], kf, sa[s], 0, 0, 0);
      }
    }
    __builtin_amdgcn_s_setprio(0);
    float tmax[4];
    #pragma unroll
    for (int r = 0; r < 4; r++){
      float t = fmaxf(fmaxf(sa[0][r], sa[1][r]), fmaxf(sa[2][r], sa[3][r]));
      t = fmaxf(t, __shfl_xor(t, 1));
      t = fmaxf(t, __shfl_xor(t, 2));
      t = fmaxf(t, __shfl_xor(t, 4));
      t = fmaxf(t, __shfl_xor(t, 8));
      tmax[r] = t;
    }
    bool need = (tmax[0] > mrow[0]+8.f) | (tmax[1] > mrow[1]+8.f) |
                (tmax[2] > mrow[2]+8.f) | (tmax[3] > mrow[3]+8.f);
    if (__any(need)){
      float al[4];
      #pragma unroll
      for (int r = 0; r < 4; r++){
        float mn = fmaxf(mrow[r], tmax[r]);
        al[r] = __expf(mrow[r] - mn);
        mrow[r] = mn;
        lsum[r] *= al[r];
      }
      #pragma unroll
      for (int c = 0; c < 16; c++){
        f32x4 o = oacc[c];
        o[0]*=al[0]; o[1]*=al[1]; o[2]*=al[2]; o[3]*=al[3];
        oacc[c] = o;
      }
    }
    #pragma unroll
    for (int s = 0; s < 4; s++)
      #pragma unroll
      for (int r = 0; r < 4; r++)
        sa[s][r] = __expf(sa[s][r] - mrow[r]);
    #pragma unroll
    for (int r = 0; r < 4; r++){
      float t = sa[0][r] + sa[1][r] + sa[2][r] + sa[3][r];
      t += __shfl_xor(t, 1); t += __shfl_xor(t, 2);
      t += __shfl_xor(t, 4); t += __shfl_xor(t, 8);
      lsum[r] += t;
    }
    #pragma unroll
    for (int s = 0; s < 4; s++)
      #pragma unroll
      for (int r = 0; r < 4; r++)
        lp[(lg*4 + r)*72 + s*16 + lq] = f2bf(sa[s][r]);
    __builtin_amdgcn_sched_barrier(0);
    __builtin_amdgcn_s_setprio(1);
    #pragma unroll
    for (int s2 = 0; s2 < 2; s2++){
      bf16x8 pa = *(const bf16x8*)(lp + lq*72 + s2*32 + lg*8);
      #pragma unroll
      for (int c = 0; c < 16; c++){
        bf16x8 vbf = *(const bf16x8*)(Vc + (c*16 + lq)*64 + (((s2*4 + lg) ^ swz) << 3));
        oacc[c] = __builtin_amdgcn_mfma_f32_16x16x32_bf16(pa, vbf, oacc[c], 0, 0, 0);
      }
    }
    __builtin_amdgcn_s_setprio(0);
    __builtin_amdgcn_sched_barrier(0);
    __syncthreads();
    cur ^= 1;
  }
  float inv[4];
  #pragma unroll
  for (int r = 0; r < 4; r++) inv[r] = 1.f / lsum[r];
  #pragma unroll
  for (int c = 0; c < 16; c++)
    #pragma unroll
    for (int r = 0; r < 4; r++){
      int n = n0 + w*16 + lg*4 + r;
      Op[((size_t)half*BN_ + (size_t)b*N_ + n)*C_ + c*16 + lq] = f2bf(oacc[c][r]*inv[r]);
    }
  if (lq == 0){
    #pragma unroll
    for (int r = 0; r < 4; r++){
      int n = n0 + w*16 + lg*4 + r;
      Mp[half*BN_ + b*N_ + n] = mrow[r];
      Lp[half*BN_ + b*N_ + n] = lsum[r];
    }
  }
}

__global__ __launch_bounds__(256) void k_comb2(const short* __restrict__ Op, const float* __restrict__ Mp,
    const float* __restrict__ Lp, short* __restrict__ Xa){
  int tid = threadIdx.x;
  int rg = blockIdx.x*8 + (tid>>5);
  int cc = (tid&31)*8;
  float m1 = Mp[rg], m2 = Mp[BN_ + rg];
  float l1 = Lp[rg], l2 = Lp[BN_ + rg];
  float m = fmaxf(m1, m2);
  float w1 = l1 * __expf(m1 - m);
  float w2 = l2 * __expf(m2 - m);
  float inv = 1.f/(w1 + w2);
  w1 *= inv; w2 *= inv;
  bf16x8 o1 = *(const bf16x8*)(Op + (size_t)rg*C_ + cc);
  bf16x8 o2 = *(const bf16x8*)(Op + ((size_t)BN_ + rg)*C_ + cc);
  bf16x8 r;
  #pragma unroll
  for (int j = 0; j < 8; j++){
    float f = w1*bf2f(o1[j]) + w2*bf2f(o2[j]);
    r[j] = f2bf(f);
  }
  *(bf16x8*)(Xa + (size_t)rg*C_ + cc) = r;
}

// ---------------- K5: out = x + cplx * (wproj @ x_attn^T), 1024 blocks ----------------
__global__ __launch_bounds__(256) void k_proj(const float* __restrict__ x, const short* __restrict__ wpb,
    const short* __restrict__ Xa, const float* __restrict__ cplx, float* __restrict__ out){
  int b = blockIdx.z, o0 = blockIdx.y*64, n0 = blockIdx.x*64;
  int tid = threadIdx.x, w = tid>>6, l = tid&63, lq = l&15, lg = l>>4;
  f32x4 zero = {0.f,0.f,0.f,0.f};
  f32x4 acc[4];
  #pragma unroll
  for (int s = 0; s < 4; s++) acc[s] = zero;
  int orow = o0 + w*16 + lq;
  for (int kk = 0; kk < 8; kk++){
    int c0 = kk*32 + lg*8;
    bf16x8 aw = *(const bf16x8*)(wpb + orow*C_ + c0);
    #pragma unroll
    for (int s = 0; s < 4; s++){
      bf16x8 xb = *(const bf16x8*)(Xa + ((size_t)b*N_ + n0 + s*16 + lq)*C_ + c0);
      acc[s] = __builtin_amdgcn_mfma_f32_16x16x32_bf16(aw, xb, acc[s], 0, 0, 0);
    }
  }
  float cp = cplx[b];
  #pragma unroll
  for (int s = 0; s < 4; s++)
    #pragma unroll
    for (int r = 0; r < 4; r++){
      int o = o0 + w*16 + lg*4 + r;
      int n = n0 + s*16 + lq;
      size_t idx = ((size_t)b*C_ + o)*N_ + n;
      out[idx] = x[idx] + cp*acc[s][r];
    }
}

extern "C" void kernel_launch(void* const* d_in, const int* in_sizes, int n_in,
                              void* d_out, int out_size, void* d_ws, size_t ws_size,
                              hipStream_t stream){
  const float* x     = (const float*)d_in[0];
  const float* w_ce1 = (const float*)d_in[1];
  const float* w_ce2 = (const float*)d_in[2];
  const float* wq    = (const float*)d_in[3];
  const float* wk    = (const float*)d_in[4];
  const float* wv    = (const float*)d_in[5];
  const float* wproj = (const float*)d_in[6];
  float* out = (float*)d_out;

  const size_t mat = (size_t)B_*N_*C_;
  const size_t needA = (3*mat + 4*mat + 4*(size_t)C_*C_)*2 + (8*(size_t)BN_ + B_*C_ + 16)*4;
  bool use4 = ws_size >= needA;
  int nparts = use4 ? 4 : 2;

  char* p = (char*)d_ws;
  short* Q   = (short*)p;            p += mat*2;
  short* K   = (short*)p;            p += mat*2;
  short* Vt  = (short*)p;            p += mat*2;
  short* Op  = (short*)p;            p += (size_t)nparts*mat*2;
  float* Mp  = (float*)p;            p += (size_t)nparts*BN_*4;
  float* Lp  = (float*)p;            p += (size_t)nparts*BN_*4;
  float* feat= (float*)p;            p += B_*C_*4;
  float* cplx= (float*)p;            p += 64;
  short* wqb = (short*)p;            p += (size_t)C_*C_*2;
  short* wkb = (short*)p;            p += (size_t)C_*C_*2;
  short* wvb = (short*)p;            p += (size_t)C_*C_*2;
  short* wpb = (short*)p;
  short* Xa  = Q; // alias: Q dead after k_attn

  const int SMEM_A4 = 65536;                                  // 64 KiB dbuf (K+V, KVBLK=32)
  const int SMEM_A2 = (16384*2 + 16384*2 + 8*16*72) * 2;      // 149504
  hipFuncSetAttribute((const void*)k_attn4, hipFuncAttributeMaxDynamicSharedMemorySize, SMEM_A4);
  hipFuncSetAttribute((const void*)k_attn2, hipFuncAttributeMaxDynamicSharedMemorySize, SMEM_A2);

  hipLaunchKernelGGL(k_feat, dim3(B_*C_), dim3(256), 0, stream, x, feat);
  hipLaunchKernelGGL(k_cplx, dim3(B_), dim3(64), 0, stream, feat, w_ce1, w_ce2, cplx);
  hipLaunchKernelGGL(k_wcvt, dim3(256), dim3(256), 0, stream, wq, wk, wv, wproj, wqb, wkb, wvb, wpb);
  hipLaunchKernelGGL(k_qkv, dim3(256,4), dim3(256), 0, stream, x, wqb, wkb, wvb, Q, K, Vt);
  if (use4){
    hipLaunchKernelGGL(k_attn4, dim3(256), dim3(512), SMEM_A4, stream, Q, K, Vt, Op, Mp, Lp);
    hipLaunchKernelGGL(k_comb4, dim3(BN_/8), dim3(256), 0, stream, Op, Mp, Lp, Xa);
  } else {
    hipLaunchKernelGGL(k_attn2, dim3(256), dim3(512), SMEM_A2, stream, Q, K, Vt, Op, Mp, Lp);
    hipLaunchKernelGGL(k_comb2, dim3(BN_/8), dim3(256), 0, stream, Op, Mp, Lp, Xa);
  }
  hipLaunchKernelGGL(k_proj, dim3(64,4,4), dim3(256), 0, stream, x, wpb, Xa, cplx, out);
}

// Round 13
// 175.392 us; speedup vs baseline: 1.4653x; 1.4653x over previous
//
#include <hip/hip_runtime.h>
#include <hip/hip_bf16.h>

#define B_ 4
#define C_ 256
#define N_ 4096
#define BN_ (B_*N_)

typedef float f32x4 __attribute__((ext_vector_type(4)));
typedef short bf16x8 __attribute__((ext_vector_type(8)));
typedef short short4v __attribute__((ext_vector_type(4)));
typedef int   int4v  __attribute__((ext_vector_type(4)));

static __device__ __forceinline__ short f2bf(float f){
  unsigned u = __builtin_bit_cast(unsigned, f);
  u += 0x7FFFu + ((u >> 16) & 1u);
  return (short)(u >> 16);
}
static __device__ __forceinline__ float bf2f(short s){
  unsigned u = ((unsigned)(unsigned short)s) << 16;
  return __builtin_bit_cast(float, u);
}
static __device__ __forceinline__ int cvtpk(float lo, float hi){
  int r;
  asm("v_cvt_pk_bf16_f32 %0, %1, %2" : "=v"(r) : "v"(lo), "v"(hi));
  return r;
}
static __device__ __forceinline__ void gload_lds16(const void* g, void* l){
  __builtin_amdgcn_global_load_lds((const __attribute__((address_space(1))) unsigned*)g,
                                   (__attribute__((address_space(3))) unsigned*)l, 16, 0, 0);
}

// ---------------- K1: feat = mean + max over (h,w) ----------------
__global__ __launch_bounds__(256) void k_feat(const float* __restrict__ x, float* __restrict__ feat){
  int row = blockIdx.x; // b*C + c
  const f32x4* p = (const f32x4*)(x + (size_t)row * N_);
  float s = 0.f, mx = -1e30f;
  for (int i = threadIdx.x; i < N_/4; i += 256){
    f32x4 v = p[i];
    s += v.x + v.y + v.z + v.w;
    mx = fmaxf(mx, fmaxf(fmaxf(v.x, v.y), fmaxf(v.z, v.w)));
  }
  __shared__ float ss[256];
  __shared__ float sm[256];
  int t = threadIdx.x;
  ss[t] = s; sm[t] = mx;
  __syncthreads();
  for (int off = 128; off > 0; off >>= 1){
    if (t < off){ ss[t] += ss[t+off]; sm[t] = fmaxf(sm[t], sm[t+off]); }
    __syncthreads();
  }
  if (t == 0) feat[row] = ss[0] * (1.f/(float)N_) + sm[0];
}

// ---------------- K2: complexity gate ----------------
__global__ __launch_bounds__(64) void k_cplx(const float* __restrict__ feat, const float* __restrict__ w1,
    const float* __restrict__ w2, float* __restrict__ cplx){
  int b = blockIdx.x, l = threadIdx.x;
  float contrib = 0.f;
  if (l < 32){
    const float* wr = w1 + l*C_;
    const float* f = feat + b*C_;
    float d = 0.f;
    for (int c = 0; c < C_; c++) d += wr[c]*f[c];
    float sg = 1.f/(1.f + expf(-d));
    contrib = (d*sg)*w2[l];
  }
  #pragma unroll
  for (int off = 1; off < 64; off <<= 1) contrib += __shfl_xor(contrib, off);
  if (l == 0) cplx[b] = 1.f/(1.f + expf(-contrib));
}

// ---------------- K2b: convert weights to bf16 ----------------
__global__ __launch_bounds__(256) void k_wcvt(const float* __restrict__ a, const float* __restrict__ b,
    const float* __restrict__ c, const float* __restrict__ d,
    short* __restrict__ oa, short* __restrict__ ob2, short* __restrict__ oc, short* __restrict__ od){
  int m = blockIdx.x >> 6;
  int off = (blockIdx.x & 63)*1024 + threadIdx.x*4;
  const float* src = (m==0)?a:(m==1)?b:(m==2)?c:d;
  short* dst = (m==0)?oa:(m==1)?ob2:(m==2)?oc:od;
  f32x4 v = *(const f32x4*)(src + off);
  short4v s;
  #pragma unroll
  for (int j = 0; j < 4; j++) s[j] = f2bf(v[j]);
  *(short4v*)(dst + off) = s;
}

// ---------------- K3: fused QKV projection (1024 blocks, bf16 weights) ----------------
__global__ __launch_bounds__(256) void k_qkv(const float* __restrict__ x,
    const short* __restrict__ wqb, const short* __restrict__ wkb, const short* __restrict__ wvb,
    short* __restrict__ Q, short* __restrict__ K, short* __restrict__ Vt){
  int b = blockIdx.z, o0 = blockIdx.y*64, n0 = blockIdx.x*64;
  int tid = threadIdx.x, w = tid>>6, l = tid&63, lq = l&15, lg = l>>4;
  const float* xb = x + (size_t)b*C_*N_;
  int nrow = n0 + w*16 + lq;
  f32x4 zero = {0.f,0.f,0.f,0.f};
  f32x4 acc[3][4];
  #pragma unroll
  for (int m = 0; m < 3; m++)
    #pragma unroll
    for (int s = 0; s < 4; s++) acc[m][s] = zero;

  for (int kk = 0; kk < 8; ++kk){
    int c0 = kk*32 + lg*8;
    bf16x8 a;
    #pragma unroll
    for (int j = 0; j < 8; j++) a[j] = f2bf(xb[(size_t)(c0+j)*N_ + nrow]);
    #pragma unroll
    for (int s = 0; s < 4; s++){
      int base = (o0 + s*16 + lq)*C_ + c0;
      bf16x8 aq = *(const bf16x8*)(wqb + base);
      bf16x8 ak = *(const bf16x8*)(wkb + base);
      bf16x8 av = *(const bf16x8*)(wvb + base);
      acc[0][s] = __builtin_amdgcn_mfma_f32_16x16x32_bf16(a, aq, acc[0][s], 0, 0, 0);
      acc[1][s] = __builtin_amdgcn_mfma_f32_16x16x32_bf16(a, ak, acc[1][s], 0, 0, 0);
      acc[2][s] = __builtin_amdgcn_mfma_f32_16x16x32_bf16(a, av, acc[2][s], 0, 0, 0);
    }
  }
  #pragma unroll
  for (int s = 0; s < 4; s++)
    #pragma unroll
    for (int r = 0; r < 4; r++){
      int n = n0 + w*16 + lg*4 + r;
      int o = o0 + s*16 + lq;
      size_t idx = ((size_t)b*N_ + n)*C_ + o;
      Q[idx] = f2bf(acc[0][s][r] * 0.0625f);
      K[idx] = f2bf(acc[1][s][r]);
    }
  __shared__ short lv[64][72];
  #pragma unroll
  for (int s = 0; s < 4; s++)
    #pragma unroll
    for (int r = 0; r < 4; r++)
      lv[s*16 + lq][w*16 + lg*4 + r] = f2bf(acc[2][s][r]);
  __syncthreads();
  #pragma unroll
  for (int i = 0; i < 16; i++){
    int orow = i*4 + (tid>>6);
    int ncol = tid & 63;
    Vt[((size_t)b*C_ + o0 + orow)*N_ + n0 + ncol] = lv[orow][ncol];
  }
}

// ---------------- K4: flash attention v8 "fat wave" (R8 verbatim, 91 us proven) ----------------
__global__ __launch_bounds__(512, 2) void k_attn4(const short* __restrict__ Q, const short* __restrict__ K,
    const short* __restrict__ Vt, short* __restrict__ Op, float* __restrict__ Mp, float* __restrict__ Lp){
  extern __shared__ short smem[];   // Ks[2][32][256] | Vs[2][256][32]
  short* KsBase = smem;             // 2*8192 shorts
  short* VsBase = smem + 16384;     // 2*8192 shorts

  int bid = blockIdx.x;
  int xcd = bid & 7, idx = bid >> 3;
  int b = xcd >> 1;
  int part = ((xcd & 1) << 1) | (idx & 1);
  int n0 = (idx >> 1) * 256;
  int kv0 = part * 1024;
  int tid = threadIdx.x, w = tid>>6, l = tid&63, lq = l&15, lg = l>>4;
  const short* Qb = Q + (size_t)b*N_*C_;
  const short* Kb = K + (size_t)b*N_*C_;
  const short* Vb = Vt + (size_t)b*C_*N_;

  // staging lane constants (chunk id = w*128 + i*64 + l, i in {0,1})
  int cid0 = w*128 + l;
  auto stage = [&](int buf, int m0){
    short* kd = KsBase + buf*8192 + w*1024;
    short* vd = VsBase + buf*8192 + w*1024;
    #pragma unroll
    for (int i = 0; i < 2; i++){
      int cid = cid0 + i*64;
      int krow = cid >> 5;                       // 0..31
      int kch  = (cid & 31) ^ (krow & 7);
      gload_lds16(Kb + (size_t)(m0 + krow)*C_ + kch*8, kd + i*512);
      int vrow = cid >> 2;                       // 0..255
      int vch  = (cid & 3) ^ (vrow & 3);
      gload_lds16(Vb + (size_t)vrow*N_ + m0 + vch*8, vd + i*512);
    }
  };

  // Q fragments hoisted: 2 q-tiles x 8 kk  (64 VGPR)
  bf16x8 qf[2][8];
  #pragma unroll
  for (int qt = 0; qt < 2; qt++){
    const short* qrow = Qb + (size_t)(n0 + w*32 + qt*16 + lq)*C_ + lg*8;
    #pragma unroll
    for (int kk = 0; kk < 8; kk++) qf[qt][kk] = *(const bf16x8*)(qrow + kk*32);
  }

  f32x4 zero = {0.f,0.f,0.f,0.f};
  f32x4 oacc[2][16];                 // 128 VGPR
  #pragma unroll
  for (int qt = 0; qt < 2; qt++)
    #pragma unroll
    for (int c = 0; c < 16; c++) oacc[qt][c] = zero;
  float m[2] = {-1e30f, -1e30f}, lsum[2] = {0.f, 0.f};
  int swz = lq & 7;
  int a01 = ((2*(lg & 1))*16 + lq) * 4;
  int a23 = a01 + 64;
  bool hiHalf = (l >= 32);

  stage(0, kv0);
  __syncthreads();
  int cur = 0;

  for (int mt = 0; mt < 32; mt++){
    if (mt + 1 < 32) stage(cur^1, kv0 + (mt+1)*32);
    const short* Kc = KsBase + cur*8192;
    const short* Vc = VsBase + cur*8192;

    // ---- QK^T: sa[qt][s] cols = q (lane&15), rows = k = s*16 + 4*lg + r
    f32x4 sa[2][2];
    #pragma unroll
    for (int qt = 0; qt < 2; qt++){ sa[qt][0] = zero; sa[qt][1] = zero; }
    __builtin_amdgcn_s_setprio(1);
    #pragma unroll
    for (int s = 0; s < 2; s++){
      const short* krowp = Kc + (s*16 + lq)*256;
      #pragma unroll
      for (int kk = 0; kk < 8; kk++){
        bf16x8 kf = *(const bf16x8*)(krowp + (((kk*4 + lg) ^ swz) << 3));
        sa[0][s] = __builtin_amdgcn_mfma_f32_16x16x32_bf16(kf, qf[0][kk], sa[0][s], 0, 0, 0);
        sa[1][s] = __builtin_amdgcn_mfma_f32_16x16x32_bf16(kf, qf[1][kk], sa[1][s], 0, 0, 0);
      }
    }
    __builtin_amdgcn_s_setprio(0);

    // ---- softmax per q-tile (per-lane scalar state, q = lane&15)
    int W[2][2][2];
    #pragma unroll
    for (int qt = 0; qt < 2; qt++){
      float pmax = sa[qt][0][0];
      #pragma unroll
      for (int s = 0; s < 2; s++)
        #pragma unroll
        for (int r = 0; r < 4; r++) pmax = fmaxf(pmax, sa[qt][s][r]);
      pmax = fmaxf(pmax, __shfl_xor(pmax, 16));
      pmax = fmaxf(pmax, __shfl_xor(pmax, 32));
      if (__any(pmax > m[qt] + 8.f)){
        float mn = fmaxf(m[qt], pmax);
        float al = __expf(m[qt] - mn);
        m[qt] = mn;
        lsum[qt] *= al;
        float alo[4];
        #pragma unroll
        for (int r = 0; r < 4; r++) alo[r] = __shfl(al, (l & 48) | (lg*4 + r));
        #pragma unroll
        for (int c = 0; c < 16; c++){
          f32x4 o = oacc[qt][c];
          o[0]*=alo[0]; o[1]*=alo[1]; o[2]*=alo[2]; o[3]*=alo[3];
          oacc[qt][c] = o;
        }
      }
      #pragma unroll
      for (int s = 0; s < 2; s++)
        #pragma unroll
        for (int r = 0; r < 4; r++) sa[qt][s][r] = __expf(sa[qt][s][r] - m[qt]);
      float ts = 0.f;
      #pragma unroll
      for (int s = 0; s < 2; s++) ts += sa[qt][s][0] + sa[qt][s][1] + sa[qt][s][2] + sa[qt][s][3];
      ts += __shfl_xor(ts, 16);
      ts += __shfl_xor(ts, 32);
      lsum[qt] += ts;
      #pragma unroll
      for (int s = 0; s < 2; s++){
        W[qt][s][0] = cvtpk(sa[qt][s][0], sa[qt][s][1]);
        W[qt][s][1] = cvtpk(sa[qt][s][2], sa[qt][s][3]);
      }
    }

    // ---- P repack to A-frag via bpermute (per q-tile)
    bf16x8 pa[2];
    #pragma unroll
    for (int qt = 0; qt < 2; qt++){
      int lo0 = __builtin_amdgcn_ds_bpermute(a01, W[qt][0][0]);
      int hi0 = __builtin_amdgcn_ds_bpermute(a01, W[qt][1][0]);
      int lo1 = __builtin_amdgcn_ds_bpermute(a01, W[qt][0][1]);
      int hi1 = __builtin_amdgcn_ds_bpermute(a01, W[qt][1][1]);
      int lo2 = __builtin_amdgcn_ds_bpermute(a23, W[qt][0][0]);
      int hi2 = __builtin_amdgcn_ds_bpermute(a23, W[qt][1][0]);
      int lo3 = __builtin_amdgcn_ds_bpermute(a23, W[qt][0][1]);
      int hi3 = __builtin_amdgcn_ds_bpermute(a23, W[qt][1][1]);
      int4v pw;
      pw[0] = hiHalf ? hi0 : lo0;
      pw[1] = hiHalf ? hi1 : lo1;
      pw[2] = hiHalf ? hi2 : lo2;
      pw[3] = hiHalf ? hi3 : lo3;
      pa[qt] = __builtin_bit_cast(bf16x8, pw);
    }

    // ---- PV: V B-frag from LDS, shared across both q-tiles
    __builtin_amdgcn_s_setprio(1);
    #pragma unroll
    for (int c = 0; c < 16; c++){
      int vr = c*16 + lq;
      bf16x8 vbf = *(const bf16x8*)(Vc + vr*32 + ((lg ^ (vr & 3)) << 3));
      oacc[0][c] = __builtin_amdgcn_mfma_f32_16x16x32_bf16(pa[0], vbf, oacc[0][c], 0, 0, 0);
      oacc[1][c] = __builtin_amdgcn_mfma_f32_16x16x32_bf16(pa[1], vbf, oacc[1][c], 0, 0, 0);
    }
    __builtin_amdgcn_s_setprio(0);

    __syncthreads();   // readers done with buf cur; staged loads for cur^1 drained
    cur ^= 1;
  }

  #pragma unroll
  for (int qt = 0; qt < 2; qt++){
    float inv = 1.f / lsum[qt];
    float invo[4];
    #pragma unroll
    for (int r = 0; r < 4; r++) invo[r] = __shfl(inv, (l & 48) | (lg*4 + r));
    #pragma unroll
    for (int c = 0; c < 16; c++)
      #pragma unroll
      for (int r = 0; r < 4; r++){
        int n = n0 + w*32 + qt*16 + lg*4 + r;
        Op[((size_t)part*BN_ + (size_t)b*N_ + n)*C_ + c*16 + lq] = f2bf(oacc[qt][c][r]*invo[r]);
      }
    if (lg == 0){
      int n = n0 + w*32 + qt*16 + lq;
      Mp[part*BN_ + b*N_ + n] = m[qt];
      Lp[part*BN_ + b*N_ + n] = lsum[qt];
    }
  }
}

// ---------------- K4b: combine 4 KV quarters ----------------
__global__ __launch_bounds__(256) void k_comb4(const short* __restrict__ Op, const float* __restrict__ Mp,
    const float* __restrict__ Lp, short* __restrict__ Xa){
  int tid = threadIdx.x;
  int rg = blockIdx.x*8 + (tid>>5);
  int cc = (tid&31)*8;
  float mv[4], lv[4];
  float m = -1e30f;
  #pragma unroll
  for (int p = 0; p < 4; p++){ mv[p] = Mp[p*BN_ + rg]; lv[p] = Lp[p*BN_ + rg]; m = fmaxf(m, mv[p]); }
  float wgt[4], wsum = 0.f;
  #pragma unroll
  for (int p = 0; p < 4; p++){ wgt[p] = lv[p]*__expf(mv[p]-m); wsum += wgt[p]; }
  float inv = 1.f/wsum;
  float acc[8];
  #pragma unroll
  for (int j = 0; j < 8; j++) acc[j] = 0.f;
  #pragma unroll
  for (int p = 0; p < 4; p++){
    bf16x8 o = *(const bf16x8*)(Op + ((size_t)p*BN_ + rg)*C_ + cc);
    #pragma unroll
    for (int j = 0; j < 8; j++) acc[j] += wgt[p]*bf2f(o[j]);
  }
  bf16x8 r;
  #pragma unroll
  for (int j = 0; j < 8; j++) r[j] = f2bf(acc[j]*inv);
  *(bf16x8*)(Xa + (size_t)rg*C_ + cc) = r;
}

// ---------------- K4 fallback (R4-proven): 2-way split, dbuf K+V in LDS ----------------
__global__ __launch_bounds__(512) void k_attn2(const short* __restrict__ Q, const short* __restrict__ K,
    const short* __restrict__ Vt, short* __restrict__ Op, float* __restrict__ Mp, float* __restrict__ Lp){
  extern __shared__ short smem[];
  short* Ks = smem;
  short* Vs = smem + 32768;
  int bid = blockIdx.x;
  int xcd = bid & 7;
  int b = xcd >> 1;
  int half = xcd & 1;
  int n0 = (bid >> 3) * 128;
  int kv0 = half * 2048;
  int tid = threadIdx.x, w = tid>>6, l = tid&63, lq = l&15, lg = l>>4;
  const short* Qb = Q + (size_t)b*N_*C_;
  const short* Kb = K + (size_t)b*N_*C_;
  const short* Vb = Vt + (size_t)b*C_*N_;
  short* lp = smem + 65536 + w*(16*72);
  int krow0 = w*8 + (l>>5);
  int kchunk0 = l&31;
  int vrow0 = w*32 + (l>>3);
  int vchunk = (l&7) ^ ((l>>3)&7);
  bf16x8 qf[8];
  {
    const short* qrow = Qb + (size_t)(n0 + w*16 + lq)*C_ + lg*8;
    #pragma unroll
    for (int kk = 0; kk < 8; kk++) qf[kk] = *(const bf16x8*)(qrow + kk*32);
  }
  f32x4 zero = {0.f,0.f,0.f,0.f};
  f32x4 oacc[16];
  #pragma unroll
  for (int c = 0; c < 16; c++) oacc[c] = zero;
  float mrow[4], lsum[4];
  #pragma unroll
  for (int r = 0; r < 4; r++){ mrow[r] = -1e30f; lsum[r] = 0.f; }
  int swz = lq & 7;
  auto stage = [&](int buf, int m0){
    short* kd = Ks + buf*16384 + w*2048;
    short* vd = Vs + buf*16384 + w*2048;
    #pragma unroll
    for (int i = 0; i < 4; i++){
      int row = krow0 + i*2;
      int chunk = kchunk0 ^ (row & 7);
      gload_lds16(Kb + (size_t)(m0 + row)*C_ + chunk*8, kd + i*512);
    }
    #pragma unroll
    for (int i = 0; i < 4; i++){
      int row = vrow0 + i*8;
      gload_lds16(Vb + (size_t)row*N_ + m0 + vchunk*8, vd + i*512);
    }
  };
  stage(0, kv0);
  __syncthreads();
  int cur = 0;
  for (int mt = 0; mt < 32; mt++){
    if (mt + 1 < 32) stage(cur^1, kv0 + (mt+1)*64);
    const short* Kc = Ks + cur*16384;
    const short* Vc = Vs + cur*16384;
    f32x4 sa[4];
    #pragma unroll
    for (int s = 0; s < 4; s++) sa[s] = zero;
    __builtin_amdgcn_s_setprio(1);
    #pragma unroll
    for (int s = 0; s < 4; s++){
      const short* krowp = Kc + (s*16 + lq)*256;
      #pragma unroll
      for (int kk = 0; kk < 8; kk++){
        bf16x8 kf = *(const bf16x8*)(krowp + (((kk*4 + lg) ^ swz) << 3));
        sa[s] = __builtin_amdgcn_mfma_f32_16x16x32_bf16(qf[kk], kf, sa[s], 0, 0, 0);
      }
    }
    __builtin_amdgcn_s_setprio(0);
    float tmax[4];
    #pragma unroll
    for (int r = 0; r < 4; r++){
      float t = fmaxf(fmaxf(sa[0][r], sa[1][r]), fmaxf(sa[2][r], sa[3][r]));
      t = fmaxf(t, __shfl_xor(t, 1));
      t = fmaxf(t, __shfl_xor(t, 2));
      t = fmaxf(t, __shfl_xor(t, 4));
      t = fmaxf(t, __shfl_xor(t, 8));
      tmax[r] = t;
    }
    bool need = (tmax[0] > mrow[0]+8.f) | (tmax[1] > mrow[1]+8.f) |
                (tmax[2] > mrow[2]+8.f) | (tmax[3] > mrow[3]+8.f);
    if (__any(need)){
      float al[4];
      #pragma unroll
      for (int r = 0; r < 4; r++){
        float mn = fmaxf(mrow[r], tmax[r]);
        al[r] = __expf(mrow[r] - mn);
        mrow[r] = mn;
        lsum[r] *= al[r];
      }
      #pragma unroll
      for (int c = 0; c < 16; c++){
        f32x4 o = oacc[c];
        o[0]*=al[0]; o[1]*=al[1]; o[2]*=al[2]; o[3]*=al[3];
        oacc[c] = o;
      }
    }
    #pragma unroll
    for (int s = 0; s < 4; s++)
      #pragma unroll
      for (int r = 0; r < 4; r++)
        sa[s][r] = __expf(sa[s][r] - mrow[r]);
    #pragma unroll
    for (int r = 0; r < 4; r++){
      float t = sa[0][r] + sa[1][r] + sa[2][r] + sa[3][r];
      t += __shfl_xor(t, 1); t += __shfl_xor(t, 2);
      t += __shfl_xor(t, 4); t += __shfl_xor(t, 8);
      lsum[r] += t;
    }
    #pragma unroll
    for (int s = 0; s < 4; s++)
      #pragma unroll
      for (int r = 0; r < 4; r++)
        lp[(lg*4 + r)*72 + s*16 + lq] = f2bf(sa[s][r]);
    __builtin_amdgcn_sched_barrier(0);
    __builtin_amdgcn_s_setprio(1);
    #pragma unroll
    for (int s2 = 0; s2 < 2; s2++){
      bf16x8 pa = *(const bf16x8*)(lp + lq*72 + s2*32 + lg*8);
      #pragma unroll
      for (int c = 0; c < 16; c++){
        bf16x8 vbf = *(const bf16x8*)(Vc + (c*16 + lq)*64 + (((s2*4 + lg) ^ swz) << 3));
        oacc[c] = __builtin_amdgcn_mfma_f32_16x16x32_bf16(pa, vbf, oacc[c], 0, 0, 0);
      }
    }
    __builtin_amdgcn_s_setprio(0);
    __builtin_amdgcn_sched_barrier(0);
    __syncthreads();
    cur ^= 1;
  }
  float inv[4];
  #pragma unroll
  for (int r = 0; r < 4; r++) inv[r] = 1.f / lsum[r];
  #pragma unroll
  for (int c = 0; c < 16; c++)
    #pragma unroll
    for (int r = 0; r < 4; r++){
      int n = n0 + w*16 + lg*4 + r;
      Op[((size_t)half*BN_ + (size_t)b*N_ + n)*C_ + c*16 + lq] = f2bf(oacc[c][r]*inv[r]);
    }
  if (lq == 0){
    #pragma unroll
    for (int r = 0; r < 4; r++){
      int n = n0 + w*16 + lg*4 + r;
      Mp[half*BN_ + b*N_ + n] = mrow[r];
      Lp[half*BN_ + b*N_ + n] = lsum[r];
    }
  }
}

__global__ __launch_bounds__(256) void k_comb2(const short* __restrict__ Op, const float* __restrict__ Mp,
    const float* __restrict__ Lp, short* __restrict__ Xa){
  int tid = threadIdx.x;
  int rg = blockIdx.x*8 + (tid>>5);
  int cc = (tid&31)*8;
  float m1 = Mp[rg], m2 = Mp[BN_ + rg];
  float l1 = Lp[rg], l2 = Lp[BN_ + rg];
  float m = fmaxf(m1, m2);
  float w1 = l1 * __expf(m1 - m);
  float w2 = l2 * __expf(m2 - m);
  float inv = 1.f/(w1 + w2);
  w1 *= inv; w2 *= inv;
  bf16x8 o1 = *(const bf16x8*)(Op + (size_t)rg*C_ + cc);
  bf16x8 o2 = *(const bf16x8*)(Op + ((size_t)BN_ + rg)*C_ + cc);
  bf16x8 r;
  #pragma unroll
  for (int j = 0; j < 8; j++){
    float f = w1*bf2f(o1[j]) + w2*bf2f(o2[j]);
    r[j] = f2bf(f);
  }
  *(bf16x8*)(Xa + (size_t)rg*C_ + cc) = r;
}

// ---------------- K5: out = x + cplx * (wproj @ x_attn^T), 1024 blocks ----------------
__global__ __launch_bounds__(256) void k_proj(const float* __restrict__ x, const short* __restrict__ wpb,
    const short* __restrict__ Xa, const float* __restrict__ cplx, float* __restrict__ out){
  int b = blockIdx.z, o0 = blockIdx.y*64, n0 = blockIdx.x*64;
  int tid = threadIdx.x, w = tid>>6, l = tid&63, lq = l&15, lg = l>>4;
  f32x4 zero = {0.f,0.f,0.f,0.f};
  f32x4 acc[4];
  #pragma unroll
  for (int s = 0; s < 4; s++) acc[s] = zero;
  int orow = o0 + w*16 + lq;
  for (int kk = 0; kk < 8; kk++){
    int c0 = kk*32 + lg*8;
    bf16x8 aw = *(const bf16x8*)(wpb + orow*C_ + c0);
    #pragma unroll
    for (int s = 0; s < 4; s++){
      bf16x8 xb = *(const bf16x8*)(Xa + ((size_t)b*N_ + n0 + s*16 + lq)*C_ + c0);
      acc[s] = __builtin_amdgcn_mfma_f32_16x16x32_bf16(aw, xb, acc[s], 0, 0, 0);
    }
  }
  float cp = cplx[b];
  #pragma unroll
  for (int s = 0; s < 4; s++)
    #pragma unroll
    for (int r = 0; r < 4; r++){
      int o = o0 + w*16 + lg*4 + r;
      int n = n0 + s*16 + lq;
      size_t idx = ((size_t)b*C_ + o)*N_ + n;
      out[idx] = x[idx] + cp*acc[s][r];
    }
}

extern "C" void kernel_launch(void* const* d_in, const int* in_sizes, int n_in,
                              void* d_out, int out_size, void* d_ws, size_t ws_size,
                              hipStream_t stream){
  const float* x     = (const float*)d_in[0];
  const float* w_ce1 = (const float*)d_in[1];
  const float* w_ce2 = (const float*)d_in[2];
  const float* wq    = (const float*)d_in[3];
  const float* wk    = (const float*)d_in[4];
  const float* wv    = (const float*)d_in[5];
  const float* wproj = (const float*)d_in[6];
  float* out = (float*)d_out;

  const size_t mat = (size_t)B_*N_*C_;
  const size_t needA = (3*mat + 4*mat + 4*(size_t)C_*C_)*2 + (8*(size_t)BN_ + B_*C_ + 16)*4;
  bool use4 = ws_size >= needA;
  int nparts = use4 ? 4 : 2;

  char* p = (char*)d_ws;
  short* Q   = (short*)p;            p += mat*2;
  short* K   = (short*)p;            p += mat*2;
  short* Vt  = (short*)p;            p += mat*2;
  short* Op  = (short*)p;            p += (size_t)nparts*mat*2;
  float* Mp  = (float*)p;            p += (size_t)nparts*BN_*4;
  float* Lp  = (float*)p;            p += (size_t)nparts*BN_*4;
  float* feat= (float*)p;            p += B_*C_*4;
  float* cplx= (float*)p;            p += 64;
  short* wqb = (short*)p;            p += (size_t)C_*C_*2;
  short* wkb = (short*)p;            p += (size_t)C_*C_*2;
  short* wvb = (short*)p;            p += (size_t)C_*C_*2;
  short* wpb = (short*)p;
  short* Xa  = Q; // alias: Q dead after k_attn

  const int SMEM_A4 = 65536;                                  // 64 KiB dbuf (K+V, KVBLK=32)
  const int SMEM_A2 = (16384*2 + 16384*2 + 8*16*72) * 2;      // 149504
  hipFuncSetAttribute((const void*)k_attn4, hipFuncAttributeMaxDynamicSharedMemorySize, SMEM_A4);
  hipFuncSetAttribute((const void*)k_attn2, hipFuncAttributeMaxDynamicSharedMemorySize, SMEM_A2);

  hipLaunchKernelGGL(k_feat, dim3(B_*C_), dim3(256), 0, stream, x, feat);
  hipLaunchKernelGGL(k_cplx, dim3(B_), dim3(64), 0, stream, feat, w_ce1, w_ce2, cplx);
  hipLaunchKernelGGL(k_wcvt, dim3(256), dim3(256), 0, stream, wq, wk, wv, wproj, wqb, wkb, wvb, wpb);
  hipLaunchKernelGGL(k_qkv, dim3(64,4,4), dim3(256), 0, stream, x, wqb, wkb, wvb, Q, K, Vt);
  if (use4){
    hipLaunchKernelGGL(k_attn4, dim3(256), dim3(512), SMEM_A4, stream, Q, K, Vt, Op, Mp, Lp);
    hipLaunchKernelGGL(k_comb4, dim3(BN_/8), dim3(256), 0, stream, Op, Mp, Lp, Xa);
  } else {
    hipLaunchKernelGGL(k_attn2, dim3(256), dim3(512), SMEM_A2, stream, Q, K, Vt, Op, Mp, Lp);
    hipLaunchKernelGGL(k_comb2, dim3(BN_/8), dim3(256), 0, stream, Op, Mp, Lp, Xa);
  }
  hipLaunchKernelGGL(k_proj, dim3(64,4,4), dim3(256), 0, stream, x, wpb, Xa, cplx, out);
}

// Round 14
// 173.108 us; speedup vs baseline: 1.4846x; 1.0132x over previous
//
#include <hip/hip_runtime.h>
#include <hip/hip_bf16.h>

#define B_ 4
#define C_ 256
#define N_ 4096
#define BN_ (B_*N_)

typedef float f32x4 __attribute__((ext_vector_type(4)));
typedef short bf16x8 __attribute__((ext_vector_type(8)));
typedef short short4v __attribute__((ext_vector_type(4)));
typedef int   int4v  __attribute__((ext_vector_type(4)));

static __device__ __forceinline__ short f2bf(float f){
  unsigned u = __builtin_bit_cast(unsigned, f);
  u += 0x7FFFu + ((u >> 16) & 1u);
  return (short)(u >> 16);
}
static __device__ __forceinline__ float bf2f(short s){
  unsigned u = ((unsigned)(unsigned short)s) << 16;
  return __builtin_bit_cast(float, u);
}
static __device__ __forceinline__ int cvtpk(float lo, float hi){
  int r;
  asm("v_cvt_pk_bf16_f32 %0, %1, %2" : "=v"(r) : "v"(lo), "v"(hi));
  return r;
}
static __device__ __forceinline__ void gload_lds16(const void* g, void* l){
  __builtin_amdgcn_global_load_lds((const __attribute__((address_space(1))) unsigned*)g,
                                   (__attribute__((address_space(3))) unsigned*)l, 16, 0, 0);
}

// ---------------- K1: feat = mean + max over (h,w) ----------------
__global__ __launch_bounds__(256) void k_feat(const float* __restrict__ x, float* __restrict__ feat){
  int row = blockIdx.x; // b*C + c
  const f32x4* p = (const f32x4*)(x + (size_t)row * N_);
  float s = 0.f, mx = -1e30f;
  for (int i = threadIdx.x; i < N_/4; i += 256){
    f32x4 v = p[i];
    s += v.x + v.y + v.z + v.w;
    mx = fmaxf(mx, fmaxf(fmaxf(v.x, v.y), fmaxf(v.z, v.w)));
  }
  __shared__ float ss[256];
  __shared__ float sm[256];
  int t = threadIdx.x;
  ss[t] = s; sm[t] = mx;
  __syncthreads();
  for (int off = 128; off > 0; off >>= 1){
    if (t < off){ ss[t] += ss[t+off]; sm[t] = fmaxf(sm[t], sm[t+off]); }
    __syncthreads();
  }
  if (t == 0) feat[row] = ss[0] * (1.f/(float)N_) + sm[0];
}

// ---------------- K2: complexity gate ----------------
__global__ __launch_bounds__(64) void k_cplx(const float* __restrict__ feat, const float* __restrict__ w1,
    const float* __restrict__ w2, float* __restrict__ cplx){
  int b = blockIdx.x, l = threadIdx.x;
  float contrib = 0.f;
  if (l < 32){
    const float* wr = w1 + l*C_;
    const float* f = feat + b*C_;
    float d = 0.f;
    for (int c = 0; c < C_; c++) d += wr[c]*f[c];
    float sg = 1.f/(1.f + expf(-d));
    contrib = (d*sg)*w2[l];
  }
  #pragma unroll
  for (int off = 1; off < 64; off <<= 1) contrib += __shfl_xor(contrib, off);
  if (l == 0) cplx[b] = 1.f/(1.f + expf(-contrib));
}

// ---------------- K2b: convert weights to bf16 ----------------
__global__ __launch_bounds__(256) void k_wcvt(const float* __restrict__ a, const float* __restrict__ b,
    const float* __restrict__ c, const float* __restrict__ d,
    short* __restrict__ oa, short* __restrict__ ob2, short* __restrict__ oc, short* __restrict__ od){
  int m = blockIdx.x >> 6;
  int off = (blockIdx.x & 63)*1024 + threadIdx.x*4;
  const float* src = (m==0)?a:(m==1)?b:(m==2)?c:d;
  short* dst = (m==0)?oa:(m==1)?ob2:(m==2)?oc:od;
  f32x4 v = *(const f32x4*)(src + off);
  short4v s;
  #pragma unroll
  for (int j = 0; j < 4; j++) s[j] = f2bf(v[j]);
  *(short4v*)(dst + off) = s;
}

// ---------------- K3: fused QKV projection (1024 blocks, bf16 weights) ----------------
__global__ __launch_bounds__(256) void k_qkv(const float* __restrict__ x,
    const short* __restrict__ wqb, const short* __restrict__ wkb, const short* __restrict__ wvb,
    short* __restrict__ Q, short* __restrict__ K, short* __restrict__ Vt){
  int b = blockIdx.z, o0 = blockIdx.y*64, n0 = blockIdx.x*64;
  int tid = threadIdx.x, w = tid>>6, l = tid&63, lq = l&15, lg = l>>4;
  const float* xb = x + (size_t)b*C_*N_;
  int nrow = n0 + w*16 + lq;
  f32x4 zero = {0.f,0.f,0.f,0.f};
  f32x4 acc[3][4];
  #pragma unroll
  for (int m = 0; m < 3; m++)
    #pragma unroll
    for (int s = 0; s < 4; s++) acc[m][s] = zero;

  for (int kk = 0; kk < 8; ++kk){
    int c0 = kk*32 + lg*8;
    bf16x8 a;
    #pragma unroll
    for (int j = 0; j < 8; j++) a[j] = f2bf(xb[(size_t)(c0+j)*N_ + nrow]);
    #pragma unroll
    for (int s = 0; s < 4; s++){
      int base = (o0 + s*16 + lq)*C_ + c0;
      bf16x8 aq = *(const bf16x8*)(wqb + base);
      bf16x8 ak = *(const bf16x8*)(wkb + base);
      bf16x8 av = *(const bf16x8*)(wvb + base);
      acc[0][s] = __builtin_amdgcn_mfma_f32_16x16x32_bf16(a, aq, acc[0][s], 0, 0, 0);
      acc[1][s] = __builtin_amdgcn_mfma_f32_16x16x32_bf16(a, ak, acc[1][s], 0, 0, 0);
      acc[2][s] = __builtin_amdgcn_mfma_f32_16x16x32_bf16(a, av, acc[2][s], 0, 0, 0);
    }
  }
  #pragma unroll
  for (int s = 0; s < 4; s++)
    #pragma unroll
    for (int r = 0; r < 4; r++){
      int n = n0 + w*16 + lg*4 + r;
      int o = o0 + s*16 + lq;
      size_t idx = ((size_t)b*N_ + n)*C_ + o;
      Q[idx] = f2bf(acc[0][s][r] * 0.0625f);
      K[idx] = f2bf(acc[1][s][r]);
    }
  __shared__ short lv[64][72];
  #pragma unroll
  for (int s = 0; s < 4; s++)
    #pragma unroll
    for (int r = 0; r < 4; r++)
      lv[s*16 + lq][w*16 + lg*4 + r] = f2bf(acc[2][s][r]);
  __syncthreads();
  #pragma unroll
  for (int i = 0; i < 16; i++){
    int orow = i*4 + (tid>>6);
    int ncol = tid & 63;
    Vt[((size_t)b*C_ + o0 + orow)*N_ + n0 + ncol] = lv[orow][ncol];
  }
}

// ---------------- K4: flash attention v12 ----------------
// R8 structure; P-repack gather rebuilt as permlane32_swap + ds_swizzle(lane^16)
// + cndmask: halves DS ops (16 bpermute -> 8 swizzle), moves half the gather
// to the VALU pipe. All other math identical to R8 (91 us proven).
__global__ __launch_bounds__(512, 2) void k_attn4(const short* __restrict__ Q, const short* __restrict__ K,
    const short* __restrict__ Vt, short* __restrict__ Op, float* __restrict__ Mp, float* __restrict__ Lp){
  extern __shared__ short smem[];   // Ks[2][32][256] | Vs[2][256][32]
  short* KsBase = smem;             // 2*8192 shorts
  short* VsBase = smem + 16384;     // 2*8192 shorts

  int bid = blockIdx.x;
  int xcd = bid & 7, idx = bid >> 3;
  int b = xcd >> 1;
  int part = ((xcd & 1) << 1) | (idx & 1);
  int n0 = (idx >> 1) * 256;
  int kv0 = part * 1024;
  int tid = threadIdx.x, w = tid>>6, l = tid&63, lq = l&15, lg = l>>4;
  const short* Qb = Q + (size_t)b*N_*C_;
  const short* Kb = K + (size_t)b*N_*C_;
  const short* Vb = Vt + (size_t)b*C_*N_;

  // staging lane constants (chunk id = w*128 + i*64 + l, i in {0,1})
  int cid0 = w*128 + l;
  auto stage = [&](int buf, int m0){
    short* kd = KsBase + buf*8192 + w*1024;
    short* vd = VsBase + buf*8192 + w*1024;
    #pragma unroll
    for (int i = 0; i < 2; i++){
      int cid = cid0 + i*64;
      int krow = cid >> 5;                       // 0..31
      int kch  = (cid & 31) ^ (krow & 7);
      gload_lds16(Kb + (size_t)(m0 + krow)*C_ + kch*8, kd + i*512);
      int vrow = cid >> 2;                       // 0..255
      int vch  = (cid & 3) ^ (vrow & 3);
      gload_lds16(Vb + (size_t)vrow*N_ + m0 + vch*8, vd + i*512);
    }
  };

  // Q fragments hoisted: 2 q-tiles x 8 kk  (64 VGPR)
  bf16x8 qf[2][8];
  #pragma unroll
  for (int qt = 0; qt < 2; qt++){
    const short* qrow = Qb + (size_t)(n0 + w*32 + qt*16 + lq)*C_ + lg*8;
    #pragma unroll
    for (int kk = 0; kk < 8; kk++) qf[qt][kk] = *(const bf16x8*)(qrow + kk*32);
  }

  f32x4 zero = {0.f,0.f,0.f,0.f};
  f32x4 oacc[2][16];                 // 128 VGPR
  #pragma unroll
  for (int qt = 0; qt < 2; qt++)
    #pragma unroll
    for (int c = 0; c < 16; c++) oacc[qt][c] = zero;
  float m[2] = {-1e30f, -1e30f}, lsum[2] = {0.f, 0.f};
  int swz = lq & 7;
  bool rowOdd = (lg & 1) != 0;       // rows R1,R3 (lanes 16-31, 48-63)

  stage(0, kv0);
  __syncthreads();
  int cur = 0;

  for (int mt = 0; mt < 32; mt++){
    if (mt + 1 < 32) stage(cur^1, kv0 + (mt+1)*32);
    const short* Kc = KsBase + cur*8192;
    const short* Vc = VsBase + cur*8192;

    // ---- QK^T: sa[qt][s] cols = q (lane&15), rows = k = s*16 + 4*lg + r
    f32x4 sa[2][2];
    #pragma unroll
    for (int qt = 0; qt < 2; qt++){ sa[qt][0] = zero; sa[qt][1] = zero; }
    __builtin_amdgcn_s_setprio(1);
    #pragma unroll
    for (int s = 0; s < 2; s++){
      const short* krowp = Kc + (s*16 + lq)*256;
      #pragma unroll
      for (int kk = 0; kk < 8; kk++){
        bf16x8 kf = *(const bf16x8*)(krowp + (((kk*4 + lg) ^ swz) << 3));
        sa[0][s] = __builtin_amdgcn_mfma_f32_16x16x32_bf16(kf, qf[0][kk], sa[0][s], 0, 0, 0);
        sa[1][s] = __builtin_amdgcn_mfma_f32_16x16x32_bf16(kf, qf[1][kk], sa[1][s], 0, 0, 0);
      }
    }
    __builtin_amdgcn_s_setprio(0);

    // ---- softmax per q-tile (per-lane scalar state, q = lane&15)
    int W[2][2][2];
    #pragma unroll
    for (int qt = 0; qt < 2; qt++){
      float pmax = sa[qt][0][0];
      #pragma unroll
      for (int s = 0; s < 2; s++)
        #pragma unroll
        for (int r = 0; r < 4; r++) pmax = fmaxf(pmax, sa[qt][s][r]);
      pmax = fmaxf(pmax, __shfl_xor(pmax, 16));
      pmax = fmaxf(pmax, __shfl_xor(pmax, 32));
      if (__any(pmax > m[qt] + 8.f)){
        float mn = fmaxf(m[qt], pmax);
        float al = __expf(m[qt] - mn);
        m[qt] = mn;
        lsum[qt] *= al;
        float alo[4];
        #pragma unroll
        for (int r = 0; r < 4; r++) alo[r] = __shfl(al, (l & 48) | (lg*4 + r));
        #pragma unroll
        for (int c = 0; c < 16; c++){
          f32x4 o = oacc[qt][c];
          o[0]*=alo[0]; o[1]*=alo[1]; o[2]*=alo[2]; o[3]*=alo[3];
          oacc[qt][c] = o;
        }
      }
      #pragma unroll
      for (int s = 0; s < 2; s++)
        #pragma unroll
        for (int r = 0; r < 4; r++) sa[qt][s][r] = __expf(sa[qt][s][r] - m[qt]);
      float ts = 0.f;
      #pragma unroll
      for (int s = 0; s < 2; s++) ts += sa[qt][s][0] + sa[qt][s][1] + sa[qt][s][2] + sa[qt][s][3];
      ts += __shfl_xor(ts, 16);
      ts += __shfl_xor(ts, 32);
      lsum[qt] += ts;
      #pragma unroll
      for (int s = 0; s < 2; s++){
        W[qt][s][0] = cvtpk(sa[qt][s][0], sa[qt][s][1]);
        W[qt][s][1] = cvtpk(sa[qt][s][2], sa[qt][s][3]);
      }
    }

    // ---- P repack to A-frag: permlane32_swap + ds_swizzle(lane^16) + cndmask
    // target lane (lg,lq) needs W rows: pw[p]=[x.R0,x.R2,y.R0,y.R2],
    // pw[p+2]=[x.R1,x.R3,y.R1,y.R3] where x=W[qt][0][p], y=W[qt][1][p].
    bf16x8 pa[2];
    #pragma unroll
    for (int qt = 0; qt < 2; qt++){
      int4v pw;
      #pragma unroll
      for (int p = 0; p < 2; p++){
        int xx = W[qt][0][p], yy = W[qt][1][p];
        asm volatile("v_permlane32_swap_b32 %0, %1" : "+v"(xx), "+v"(yy));
        // xx=[x0,x1,y0,y1], yy=[x2,x3,y2,y3]
        int xs = __builtin_amdgcn_ds_swizzle(xx, 0x401F); // lane^16: [x1,x0,y1,y0]
        int ys = __builtin_amdgcn_ds_swizzle(yy, 0x401F); // [x3,x2,y3,y2]
        pw[p]   = rowOdd ? ys : xx;   // [x0,x2,y0,y2]
        pw[p+2] = rowOdd ? yy : xs;   // [x1,x3,y1,y3]
      }
      pa[qt] = __builtin_bit_cast(bf16x8, pw);
    }

    // ---- PV: V B-frag from LDS, shared across both q-tiles
    __builtin_amdgcn_s_setprio(1);
    #pragma unroll
    for (int c = 0; c < 16; c++){
      int vr = c*16 + lq;
      bf16x8 vbf = *(const bf16x8*)(Vc + vr*32 + ((lg ^ (vr & 3)) << 3));
      oacc[0][c] = __builtin_amdgcn_mfma_f32_16x16x32_bf16(pa[0], vbf, oacc[0][c], 0, 0, 0);
      oacc[1][c] = __builtin_amdgcn_mfma_f32_16x16x32_bf16(pa[1], vbf, oacc[1][c], 0, 0, 0);
    }
    __builtin_amdgcn_s_setprio(0);

    __syncthreads();   // readers done with buf cur; staged loads for cur^1 drained
    cur ^= 1;
  }

  #pragma unroll
  for (int qt = 0; qt < 2; qt++){
    float inv = 1.f / lsum[qt];
    float invo[4];
    #pragma unroll
    for (int r = 0; r < 4; r++) invo[r] = __shfl(inv, (l & 48) | (lg*4 + r));
    #pragma unroll
    for (int c = 0; c < 16; c++)
      #pragma unroll
      for (int r = 0; r < 4; r++){
        int n = n0 + w*32 + qt*16 + lg*4 + r;
        Op[((size_t)part*BN_ + (size_t)b*N_ + n)*C_ + c*16 + lq] = f2bf(oacc[qt][c][r]*invo[r]);
      }
    if (lg == 0){
      int n = n0 + w*32 + qt*16 + lq;
      Mp[part*BN_ + b*N_ + n] = m[qt];
      Lp[part*BN_ + b*N_ + n] = lsum[qt];
    }
  }
}

// ---------------- K4b: combine 4 KV quarters ----------------
__global__ __launch_bounds__(256) void k_comb4(const short* __restrict__ Op, const float* __restrict__ Mp,
    const float* __restrict__ Lp, short* __restrict__ Xa){
  int tid = threadIdx.x;
  int rg = blockIdx.x*8 + (tid>>5);
  int cc = (tid&31)*8;
  float mv[4], lv[4];
  float m = -1e30f;
  #pragma unroll
  for (int p = 0; p < 4; p++){ mv[p] = Mp[p*BN_ + rg]; lv[p] = Lp[p*BN_ + rg]; m = fmaxf(m, mv[p]); }
  float wgt[4], wsum = 0.f;
  #pragma unroll
  for (int p = 0; p < 4; p++){ wgt[p] = lv[p]*__expf(mv[p]-m); wsum += wgt[p]; }
  float inv = 1.f/wsum;
  float acc[8];
  #pragma unroll
  for (int j = 0; j < 8; j++) acc[j] = 0.f;
  #pragma unroll
  for (int p = 0; p < 4; p++){
    bf16x8 o = *(const bf16x8*)(Op + ((size_t)p*BN_ + rg)*C_ + cc);
    #pragma unroll
    for (int j = 0; j < 8; j++) acc[j] += wgt[p]*bf2f(o[j]);
  }
  bf16x8 r;
  #pragma unroll
  for (int j = 0; j < 8; j++) r[j] = f2bf(acc[j]*inv);
  *(bf16x8*)(Xa + (size_t)rg*C_ + cc) = r;
}

// ---------------- K4 fallback (R4-proven): 2-way split, dbuf K+V in LDS ----------------
__global__ __launch_bounds__(512) void k_attn2(const short* __restrict__ Q, const short* __restrict__ K,
    const short* __restrict__ Vt, short* __restrict__ Op, float* __restrict__ Mp, float* __restrict__ Lp){
  extern __shared__ short smem[];
  short* Ks = smem;
  short* Vs = smem + 32768;
  int bid = blockIdx.x;
  int xcd = bid & 7;
  int b = xcd >> 1;
  int half = xcd & 1;
  int n0 = (bid >> 3) * 128;
  int kv0 = half * 2048;
  int tid = threadIdx.x, w = tid>>6, l = tid&63, lq = l&15, lg = l>>4;
  const short* Qb = Q + (size_t)b*N_*C_;
  const short* Kb = K + (size_t)b*N_*C_;
  const short* Vb = Vt + (size_t)b*C_*N_;
  short* lp = smem + 65536 + w*(16*72);
  int krow0 = w*8 + (l>>5);
  int kchunk0 = l&31;
  int vrow0 = w*32 + (l>>3);
  int vchunk = (l&7) ^ ((l>>3)&7);
  bf16x8 qf[8];
  {
    const short* qrow = Qb + (size_t)(n0 + w*16 + lq)*C_ + lg*8;
    #pragma unroll
    for (int kk = 0; kk < 8; kk++) qf[kk] = *(const bf16x8*)(qrow + kk*32);
  }
  f32x4 zero = {0.f,0.f,0.f,0.f};
  f32x4 oacc[16];
  #pragma unroll
  for (int c = 0; c < 16; c++) oacc[c] = zero;
  float mrow[4], lsum[4];
  #pragma unroll
  for (int r = 0; r < 4; r++){ mrow[r] = -1e30f; lsum[r] = 0.f; }
  int swz = lq & 7;
  auto stage = [&](int buf, int m0){
    short* kd = Ks + buf*16384 + w*2048;
    short* vd = Vs + buf*16384 + w*2048;
    #pragma unroll
    for (int i = 0; i < 4; i++){
      int row = krow0 + i*2;
      int chunk = kchunk0 ^ (row & 7);
      gload_lds16(Kb + (size_t)(m0 + row)*C_ + chunk*8, kd + i*512);
    }
    #pragma unroll
    for (int i = 0; i < 4; i++){
      int row = vrow0 + i*8;
      gload_lds16(Vb + (size_t)row*N_ + m0 + vchunk*8, vd + i*512);
    }
  };
  stage(0, kv0);
  __syncthreads();
  int cur = 0;
  for (int mt = 0; mt < 32; mt++){
    if (mt + 1 < 32) stage(cur^1, kv0 + (mt+1)*64);
    const short* Kc = Ks + cur*16384;
    const short* Vc = Vs + cur*16384;
    f32x4 sa[4];
    #pragma unroll
    for (int s = 0; s < 4; s++) sa[s] = zero;
    __builtin_amdgcn_s_setprio(1);
    #pragma unroll
    for (int s = 0; s < 4; s++){
      const short* krowp = Kc + (s*16 + lq)*256;
      #pragma unroll
      for (int kk = 0; kk < 8; kk++){
        bf16x8 kf = *(const bf16x8*)(krowp + (((kk*4 + lg) ^ swz) << 3));
        sa[s] = __builtin_amdgcn_mfma_f32_16x16x32_bf16(qf[kk], kf, sa[s], 0, 0, 0);
      }
    }
    __builtin_amdgcn_s_setprio(0);
    float tmax[4];
    #pragma unroll
    for (int r = 0; r < 4; r++){
      float t = fmaxf(fmaxf(sa[0][r], sa[1][r]), fmaxf(sa[2][r], sa[3][r]));
      t = fmaxf(t, __shfl_xor(t, 1));
      t = fmaxf(t, __shfl_xor(t, 2));
      t = fmaxf(t, __shfl_xor(t, 4));
      t = fmaxf(t, __shfl_xor(t, 8));
      tmax[r] = t;
    }
    bool need = (tmax[0] > mrow[0]+8.f) | (tmax[1] > mrow[1]+8.f) |
                (tmax[2] > mrow[2]+8.f) | (tmax[3] > mrow[3]+8.f);
    if (__any(need)){
      float al[4];
      #pragma unroll
      for (int r = 0; r < 4; r++){
        float mn = fmaxf(mrow[r], tmax[r]);
        al[r] = __expf(mrow[r] - mn);
        mrow[r] = mn;
        lsum[r] *= al[r];
      }
      #pragma unroll
      for (int c = 0; c < 16; c++){
        f32x4 o = oacc[c];
        o[0]*=al[0]; o[1]*=al[1]; o[2]*=al[2]; o[3]*=al[3];
        oacc[c] = o;
      }
    }
    #pragma unroll
    for (int s = 0; s < 4; s++)
      #pragma unroll
      for (int r = 0; r < 4; r++)
        sa[s][r] = __expf(sa[s][r] - mrow[r]);
    #pragma unroll
    for (int r = 0; r < 4; r++){
      float t = sa[0][r] + sa[1][r] + sa[2][r] + sa[3][r];
      t += __shfl_xor(t, 1); t += __shfl_xor(t, 2);
      t += __shfl_xor(t, 4); t += __shfl_xor(t, 8);
      lsum[r] += t;
    }
    #pragma unroll
    for (int s = 0; s < 4; s++)
      #pragma unroll
      for (int r = 0; r < 4; r++)
        lp[(lg*4 + r)*72 + s*16 + lq] = f2bf(sa[s][r]);
    __builtin_amdgcn_sched_barrier(0);
    __builtin_amdgcn_s_setprio(1);
    #pragma unroll
    for (int s2 = 0; s2 < 2; s2++){
      bf16x8 pa = *(const bf16x8*)(lp + lq*72 + s2*32 + lg*8);
      #pragma unroll
      for (int c = 0; c < 16; c++){
        bf16x8 vbf = *(const bf16x8*)(Vc + (c*16 + lq)*64 + (((s2*4 + lg) ^ swz) << 3));
        oacc[c] = __builtin_amdgcn_mfma_f32_16x16x32_bf16(pa, vbf, oacc[c], 0, 0, 0);
      }
    }
    __builtin_amdgcn_s_setprio(0);
    __builtin_amdgcn_sched_barrier(0);
    __syncthreads();
    cur ^= 1;
  }
  float inv[4];
  #pragma unroll
  for (int r = 0; r < 4; r++) inv[r] = 1.f / lsum[r];
  #pragma unroll
  for (int c = 0; c < 16; c++)
    #pragma unroll
    for (int r = 0; r < 4; r++){
      int n = n0 + w*16 + lg*4 + r;
      Op[((size_t)half*BN_ + (size_t)b*N_ + n)*C_ + c*16 + lq] = f2bf(oacc[c][r]*inv[r]);
    }
  if (lq == 0){
    #pragma unroll
    for (int r = 0; r < 4; r++){
      int n = n0 + w*16 + lg*4 + r;
      Mp[half*BN_ + b*N_ + n] = mrow[r];
      Lp[half*BN_ + b*N_ + n] = lsum[r];
    }
  }
}

__global__ __launch_bounds__(256) void k_comb2(const short* __restrict__ Op, const float* __restrict__ Mp,
    const float* __restrict__ Lp, short* __restrict__ Xa){
  int tid = threadIdx.x;
  int rg = blockIdx.x*8 + (tid>>5);
  int cc = (tid&31)*8;
  float m1 = Mp[rg], m2 = Mp[BN_ + rg];
  float l1 = Lp[rg], l2 = Lp[BN_ + rg];
  float m = fmaxf(m1, m2);
  float w1 = l1 * __expf(m1 - m);
  float w2 = l2 * __expf(m2 - m);
  float inv = 1.f/(w1 + w2);
  w1 *= inv; w2 *= inv;
  bf16x8 o1 = *(const bf16x8*)(Op + (size_t)rg*C_ + cc);
  bf16x8 o2 = *(const bf16x8*)(Op + ((size_t)BN_ + rg)*C_ + cc);
  bf16x8 r;
  #pragma unroll
  for (int j = 0; j < 8; j++){
    float f = w1*bf2f(o1[j]) + w2*bf2f(o2[j]);
    r[j] = f2bf(f);
  }
  *(bf16x8*)(Xa + (size_t)rg*C_ + cc) = r;
}

// ---------------- K5: out = x + cplx * (wproj @ x_attn^T), 1024 blocks ----------------
__global__ __launch_bounds__(256) void k_proj(const float* __restrict__ x, const short* __restrict__ wpb,
    const short* __restrict__ Xa, const float* __restrict__ cplx, float* __restrict__ out){
  int b = blockIdx.z, o0 = blockIdx.y*64, n0 = blockIdx.x*64;
  int tid = threadIdx.x, w = tid>>6, l = tid&63, lq = l&15, lg = l>>4;
  f32x4 zero = {0.f,0.f,0.f,0.f};
  f32x4 acc[4];
  #pragma unroll
  for (int s = 0; s < 4; s++) acc[s] = zero;
  int orow = o0 + w*16 + lq;
  for (int kk = 0; kk < 8; kk++){
    int c0 = kk*32 + lg*8;
    bf16x8 aw = *(const bf16x8*)(wpb + orow*C_ + c0);
    #pragma unroll
    for (int s = 0; s < 4; s++){
      bf16x8 xb = *(const bf16x8*)(Xa + ((size_t)b*N_ + n0 + s*16 + lq)*C_ + c0);
      acc[s] = __builtin_amdgcn_mfma_f32_16x16x32_bf16(aw, xb, acc[s], 0, 0, 0);
    }
  }
  float cp = cplx[b];
  #pragma unroll
  for (int s = 0; s < 4; s++)
    #pragma unroll
    for (int r = 0; r < 4; r++){
      int o = o0 + w*16 + lg*4 + r;
      int n = n0 + s*16 + lq;
      size_t idx = ((size_t)b*C_ + o)*N_ + n;
      out[idx] = x[idx] + cp*acc[s][r];
    }
}

extern "C" void kernel_launch(void* const* d_in, const int* in_sizes, int n_in,
                              void* d_out, int out_size, void* d_ws, size_t ws_size,
                              hipStream_t stream){
  const float* x     = (const float*)d_in[0];
  const float* w_ce1 = (const float*)d_in[1];
  const float* w_ce2 = (const float*)d_in[2];
  const float* wq    = (const float*)d_in[3];
  const float* wk    = (const float*)d_in[4];
  const float* wv    = (const float*)d_in[5];
  const float* wproj = (const float*)d_in[6];
  float* out = (float*)d_out;

  const size_t mat = (size_t)B_*N_*C_;
  const size_t needA = (3*mat + 4*mat + 4*(size_t)C_*C_)*2 + (8*(size_t)BN_ + B_*C_ + 16)*4;
  bool use4 = ws_size >= needA;
  int nparts = use4 ? 4 : 2;

  char* p = (char*)d_ws;
  short* Q   = (short*)p;            p += mat*2;
  short* K   = (short*)p;            p += mat*2;
  short* Vt  = (short*)p;            p += mat*2;
  short* Op  = (short*)p;            p += (size_t)nparts*mat*2;
  float* Mp  = (float*)p;            p += (size_t)nparts*BN_*4;
  float* Lp  = (float*)p;            p += (size_t)nparts*BN_*4;
  float* feat= (float*)p;            p += B_*C_*4;
  float* cplx= (float*)p;            p += 64;
  short* wqb = (short*)p;            p += (size_t)C_*C_*2;
  short* wkb = (short*)p;            p += (size_t)C_*C_*2;
  short* wvb = (short*)p;            p += (size_t)C_*C_*2;
  short* wpb = (short*)p;
  short* Xa  = Q; // alias: Q dead after k_attn

  const int SMEM_A4 = 65536;                                  // 64 KiB dbuf (K+V, KVBLK=32)
  const int SMEM_A2 = (16384*2 + 16384*2 + 8*16*72) * 2;      // 149504
  hipFuncSetAttribute((const void*)k_attn4, hipFuncAttributeMaxDynamicSharedMemorySize, SMEM_A4);
  hipFuncSetAttribute((const void*)k_attn2, hipFuncAttributeMaxDynamicSharedMemorySize, SMEM_A2);

  hipLaunchKernelGGL(k_feat, dim3(B_*C_), dim3(256), 0, stream, x, feat);
  hipLaunchKernelGGL(k_cplx, dim3(B_), dim3(64), 0, stream, feat, w_ce1, w_ce2, cplx);
  hipLaunchKernelGGL(k_wcvt, dim3(256), dim3(256), 0, stream, wq, wk, wv, wproj, wqb, wkb, wvb, wpb);
  hipLaunchKernelGGL(k_qkv, dim3(64,4,4), dim3(256), 0, stream, x, wqb, wkb, wvb, Q, K, Vt);
  if (use4){
    hipLaunchKernelGGL(k_attn4, dim3(256), dim3(512), SMEM_A4, stream, Q, K, Vt, Op, Mp, Lp);
    hipLaunchKernelGGL(k_comb4, dim3(BN_/8), dim3(256), 0, stream, Op, Mp, Lp, Xa);
  } else {
    hipLaunchKernelGGL(k_attn2, dim3(256), dim3(512), SMEM_A2, stream, Q, K, Vt, Op, Mp, Lp);
    hipLaunchKernelGGL(k_comb2, dim3(BN_/8), dim3(256), 0, stream, Op, Mp, Lp, Xa);
  }
  hipLaunchKernelGGL(k_proj, dim3(64,4,4), dim3(256), 0, stream, x, wpb, Xa, cplx, out);
}

// Round 15
// 169.552 us; speedup vs baseline: 1.5157x; 1.0210x over previous
//
#include <hip/hip_runtime.h>
#include <hip/hip_bf16.h>

#define B_ 4
#define C_ 256
#define N_ 4096
#define BN_ (B_*N_)

typedef float f32x4 __attribute__((ext_vector_type(4)));
typedef short bf16x8 __attribute__((ext_vector_type(8)));
typedef short short4v __attribute__((ext_vector_type(4)));
typedef int   int4v  __attribute__((ext_vector_type(4)));

static __device__ __forceinline__ short f2bf(float f){
  unsigned u = __builtin_bit_cast(unsigned, f);
  u += 0x7FFFu + ((u >> 16) & 1u);
  return (short)(u >> 16);
}
static __device__ __forceinline__ float bf2f(short s){
  unsigned u = ((unsigned)(unsigned short)s) << 16;
  return __builtin_bit_cast(float, u);
}
static __device__ __forceinline__ int cvtpk(float lo, float hi){
  int r;
  asm("v_cvt_pk_bf16_f32 %0, %1, %2" : "=v"(r) : "v"(lo), "v"(hi));
  return r;
}
static __device__ __forceinline__ void gload_lds16(const void* g, void* l){
  __builtin_amdgcn_global_load_lds((const __attribute__((address_space(1))) unsigned*)g,
                                   (__attribute__((address_space(3))) unsigned*)l, 16, 0, 0);
}

// ---------------- K1: feat = mean + max over (h,w) ----------------
__global__ __launch_bounds__(256) void k_feat(const float* __restrict__ x, float* __restrict__ feat){
  int row = blockIdx.x; // b*C + c
  const f32x4* p = (const f32x4*)(x + (size_t)row * N_);
  float s = 0.f, mx = -1e30f;
  for (int i = threadIdx.x; i < N_/4; i += 256){
    f32x4 v = p[i];
    s += v.x + v.y + v.z + v.w;
    mx = fmaxf(mx, fmaxf(fmaxf(v.x, v.y), fmaxf(v.z, v.w)));
  }
  __shared__ float ss[256];
  __shared__ float sm[256];
  int t = threadIdx.x;
  ss[t] = s; sm[t] = mx;
  __syncthreads();
  for (int off = 128; off > 0; off >>= 1){
    if (t < off){ ss[t] += ss[t+off]; sm[t] = fmaxf(sm[t], sm[t+off]); }
    __syncthreads();
  }
  if (t == 0) feat[row] = ss[0] * (1.f/(float)N_) + sm[0];
}

// ---------------- K2: complexity gate ----------------
__global__ __launch_bounds__(64) void k_cplx(const float* __restrict__ feat, const float* __restrict__ w1,
    const float* __restrict__ w2, float* __restrict__ cplx){
  int b = blockIdx.x, l = threadIdx.x;
  float contrib = 0.f;
  if (l < 32){
    const float* wr = w1 + l*C_;
    const float* f = feat + b*C_;
    float d = 0.f;
    for (int c = 0; c < C_; c++) d += wr[c]*f[c];
    float sg = 1.f/(1.f + expf(-d));
    contrib = (d*sg)*w2[l];
  }
  #pragma unroll
  for (int off = 1; off < 64; off <<= 1) contrib += __shfl_xor(contrib, off);
  if (l == 0) cplx[b] = 1.f/(1.f + expf(-contrib));
}

// ---------------- K2b: convert weights to bf16 ----------------
__global__ __launch_bounds__(256) void k_wcvt(const float* __restrict__ a, const float* __restrict__ b,
    const float* __restrict__ c, const float* __restrict__ d,
    short* __restrict__ oa, short* __restrict__ ob2, short* __restrict__ oc, short* __restrict__ od){
  int m = blockIdx.x >> 6;
  int off = (blockIdx.x & 63)*1024 + threadIdx.x*4;
  const float* src = (m==0)?a:(m==1)?b:(m==2)?c:d;
  short* dst = (m==0)?oa:(m==1)?ob2:(m==2)?oc:od;
  f32x4 v = *(const f32x4*)(src + off);
  short4v s;
  #pragma unroll
  for (int j = 0; j < 4; j++) s[j] = f2bf(v[j]);
  *(short4v*)(dst + off) = s;
}

// ---------------- K3: fused QKV projection (1024 blocks, bf16 weights) ----------------
__global__ __launch_bounds__(256) void k_qkv(const float* __restrict__ x,
    const short* __restrict__ wqb, const short* __restrict__ wkb, const short* __restrict__ wvb,
    short* __restrict__ Q, short* __restrict__ K, short* __restrict__ Vt){
  int b = blockIdx.z, o0 = blockIdx.y*64, n0 = blockIdx.x*64;
  int tid = threadIdx.x, w = tid>>6, l = tid&63, lq = l&15, lg = l>>4;
  const float* xb = x + (size_t)b*C_*N_;
  int nrow = n0 + w*16 + lq;
  f32x4 zero = {0.f,0.f,0.f,0.f};
  f32x4 acc[3][4];
  #pragma unroll
  for (int m = 0; m < 3; m++)
    #pragma unroll
    for (int s = 0; s < 4; s++) acc[m][s] = zero;

  for (int kk = 0; kk < 8; ++kk){
    int c0 = kk*32 + lg*8;
    bf16x8 a;
    #pragma unroll
    for (int j = 0; j < 8; j++) a[j] = f2bf(xb[(size_t)(c0+j)*N_ + nrow]);
    #pragma unroll
    for (int s = 0; s < 4; s++){
      int base = (o0 + s*16 + lq)*C_ + c0;
      bf16x8 aq = *(const bf16x8*)(wqb + base);
      bf16x8 ak = *(const bf16x8*)(wkb + base);
      bf16x8 av = *(const bf16x8*)(wvb + base);
      acc[0][s] = __builtin_amdgcn_mfma_f32_16x16x32_bf16(a, aq, acc[0][s], 0, 0, 0);
      acc[1][s] = __builtin_amdgcn_mfma_f32_16x16x32_bf16(a, ak, acc[1][s], 0, 0, 0);
      acc[2][s] = __builtin_amdgcn_mfma_f32_16x16x32_bf16(a, av, acc[2][s], 0, 0, 0);
    }
  }
  #pragma unroll
  for (int s = 0; s < 4; s++)
    #pragma unroll
    for (int r = 0; r < 4; r++){
      int n = n0 + w*16 + lg*4 + r;
      int o = o0 + s*16 + lq;
      size_t idx = ((size_t)b*N_ + n)*C_ + o;
      Q[idx] = f2bf(acc[0][s][r] * 0.0625f);
      K[idx] = f2bf(acc[1][s][r]);
    }
  __shared__ short lv[64][72];
  #pragma unroll
  for (int s = 0; s < 4; s++)
    #pragma unroll
    for (int r = 0; r < 4; r++)
      lv[s*16 + lq][w*16 + lg*4 + r] = f2bf(acc[2][s][r]);
  __syncthreads();
  #pragma unroll
  for (int i = 0; i < 16; i++){
    int orow = i*4 + (tid>>6);
    int ncol = tid & 63;
    Vt[((size_t)b*C_ + o0 + orow)*N_ + n0 + ncol] = lv[orow][ncol];
  }
}

// ---------------- K4: flash attention v13 ----------------
// R8 structure; P-repack gather now 100% VALU: permlane32_swap + permlane16_swap
// per W-pair (zero DS ops, zero cndmask). All other math identical.
__global__ __launch_bounds__(512, 2) void k_attn4(const short* __restrict__ Q, const short* __restrict__ K,
    const short* __restrict__ Vt, short* __restrict__ Op, float* __restrict__ Mp, float* __restrict__ Lp){
  extern __shared__ short smem[];   // Ks[2][32][256] | Vs[2][256][32]
  short* KsBase = smem;             // 2*8192 shorts
  short* VsBase = smem + 16384;     // 2*8192 shorts

  int bid = blockIdx.x;
  int xcd = bid & 7, idx = bid >> 3;
  int b = xcd >> 1;
  int part = ((xcd & 1) << 1) | (idx & 1);
  int n0 = (idx >> 1) * 256;
  int kv0 = part * 1024;
  int tid = threadIdx.x, w = tid>>6, l = tid&63, lq = l&15, lg = l>>4;
  const short* Qb = Q + (size_t)b*N_*C_;
  const short* Kb = K + (size_t)b*N_*C_;
  const short* Vb = Vt + (size_t)b*C_*N_;

  // staging lane constants (chunk id = w*128 + i*64 + l, i in {0,1})
  int cid0 = w*128 + l;
  auto stage = [&](int buf, int m0){
    short* kd = KsBase + buf*8192 + w*1024;
    short* vd = VsBase + buf*8192 + w*1024;
    #pragma unroll
    for (int i = 0; i < 2; i++){
      int cid = cid0 + i*64;
      int krow = cid >> 5;                       // 0..31
      int kch  = (cid & 31) ^ (krow & 7);
      gload_lds16(Kb + (size_t)(m0 + krow)*C_ + kch*8, kd + i*512);
      int vrow = cid >> 2;                       // 0..255
      int vch  = (cid & 3) ^ (vrow & 3);
      gload_lds16(Vb + (size_t)vrow*N_ + m0 + vch*8, vd + i*512);
    }
  };

  // Q fragments hoisted: 2 q-tiles x 8 kk  (64 VGPR)
  bf16x8 qf[2][8];
  #pragma unroll
  for (int qt = 0; qt < 2; qt++){
    const short* qrow = Qb + (size_t)(n0 + w*32 + qt*16 + lq)*C_ + lg*8;
    #pragma unroll
    for (int kk = 0; kk < 8; kk++) qf[qt][kk] = *(const bf16x8*)(qrow + kk*32);
  }

  f32x4 zero = {0.f,0.f,0.f,0.f};
  f32x4 oacc[2][16];                 // 128 VGPR
  #pragma unroll
  for (int qt = 0; qt < 2; qt++)
    #pragma unroll
    for (int c = 0; c < 16; c++) oacc[qt][c] = zero;
  float m[2] = {-1e30f, -1e30f}, lsum[2] = {0.f, 0.f};
  int swz = lq & 7;

  stage(0, kv0);
  __syncthreads();
  int cur = 0;

  for (int mt = 0; mt < 32; mt++){
    if (mt + 1 < 32) stage(cur^1, kv0 + (mt+1)*32);
    const short* Kc = KsBase + cur*8192;
    const short* Vc = VsBase + cur*8192;

    // ---- QK^T: sa[qt][s] cols = q (lane&15), rows = k = s*16 + 4*lg + r
    f32x4 sa[2][2];
    #pragma unroll
    for (int qt = 0; qt < 2; qt++){ sa[qt][0] = zero; sa[qt][1] = zero; }
    __builtin_amdgcn_s_setprio(1);
    #pragma unroll
    for (int s = 0; s < 2; s++){
      const short* krowp = Kc + (s*16 + lq)*256;
      #pragma unroll
      for (int kk = 0; kk < 8; kk++){
        bf16x8 kf = *(const bf16x8*)(krowp + (((kk*4 + lg) ^ swz) << 3));
        sa[0][s] = __builtin_amdgcn_mfma_f32_16x16x32_bf16(kf, qf[0][kk], sa[0][s], 0, 0, 0);
        sa[1][s] = __builtin_amdgcn_mfma_f32_16x16x32_bf16(kf, qf[1][kk], sa[1][s], 0, 0, 0);
      }
    }
    __builtin_amdgcn_s_setprio(0);

    // ---- softmax per q-tile (per-lane scalar state, q = lane&15)
    int W[2][2][2];
    #pragma unroll
    for (int qt = 0; qt < 2; qt++){
      float pmax = sa[qt][0][0];
      #pragma unroll
      for (int s = 0; s < 2; s++)
        #pragma unroll
        for (int r = 0; r < 4; r++) pmax = fmaxf(pmax, sa[qt][s][r]);
      pmax = fmaxf(pmax, __shfl_xor(pmax, 16));
      pmax = fmaxf(pmax, __shfl_xor(pmax, 32));
      if (__any(pmax > m[qt] + 8.f)){
        float mn = fmaxf(m[qt], pmax);
        float al = __expf(m[qt] - mn);
        m[qt] = mn;
        lsum[qt] *= al;
        float alo[4];
        #pragma unroll
        for (int r = 0; r < 4; r++) alo[r] = __shfl(al, (l & 48) | (lg*4 + r));
        #pragma unroll
        for (int c = 0; c < 16; c++){
          f32x4 o = oacc[qt][c];
          o[0]*=alo[0]; o[1]*=alo[1]; o[2]*=alo[2]; o[3]*=alo[3];
          oacc[qt][c] = o;
        }
      }
      #pragma unroll
      for (int s = 0; s < 2; s++)
        #pragma unroll
        for (int r = 0; r < 4; r++) sa[qt][s][r] = __expf(sa[qt][s][r] - m[qt]);
      float ts = 0.f;
      #pragma unroll
      for (int s = 0; s < 2; s++) ts += sa[qt][s][0] + sa[qt][s][1] + sa[qt][s][2] + sa[qt][s][3];
      ts += __shfl_xor(ts, 16);
      ts += __shfl_xor(ts, 32);
      lsum[qt] += ts;
      #pragma unroll
      for (int s = 0; s < 2; s++){
        W[qt][s][0] = cvtpk(sa[qt][s][0], sa[qt][s][1]);
        W[qt][s][1] = cvtpk(sa[qt][s][2], sa[qt][s][3]);
      }
    }

    // ---- P repack to A-frag: permlane32_swap then permlane16_swap (pure VALU)
    // x=[x0,x1,x2,x3] rows, y=[y0,y1,y2,y3] rows (16-lane groups).
    // After pl32: x=[x0,x1,y0,y1], y=[x2,x3,y2,y3].
    // After pl16 (vdst.row1<->src.row0, vdst.row3<->src.row2):
    //   x=[x0,x2,y0,y2] = pw[p],  y=[x1,x3,y1,y3] = pw[p+2].
    bf16x8 pa[2];
    #pragma unroll
    for (int qt = 0; qt < 2; qt++){
      int4v pw;
      #pragma unroll
      for (int p = 0; p < 2; p++){
        int xx = W[qt][0][p], yy = W[qt][1][p];
        asm volatile("v_permlane32_swap_b32 %0, %1" : "+v"(xx), "+v"(yy));
        asm volatile("v_permlane16_swap_b32 %0, %1" : "+v"(xx), "+v"(yy));
        pw[p]   = xx;
        pw[p+2] = yy;
      }
      pa[qt] = __builtin_bit_cast(bf16x8, pw);
    }

    // ---- PV: V B-frag from LDS, shared across both q-tiles
    __builtin_amdgcn_s_setprio(1);
    #pragma unroll
    for (int c = 0; c < 16; c++){
      int vr = c*16 + lq;
      bf16x8 vbf = *(const bf16x8*)(Vc + vr*32 + ((lg ^ (vr & 3)) << 3));
      oacc[0][c] = __builtin_amdgcn_mfma_f32_16x16x32_bf16(pa[0], vbf, oacc[0][c], 0, 0, 0);
      oacc[1][c] = __builtin_amdgcn_mfma_f32_16x16x32_bf16(pa[1], vbf, oacc[1][c], 0, 0, 0);
    }
    __builtin_amdgcn_s_setprio(0);

    __syncthreads();   // readers done with buf cur; staged loads for cur^1 drained
    cur ^= 1;
  }

  #pragma unroll
  for (int qt = 0; qt < 2; qt++){
    float inv = 1.f / lsum[qt];
    float invo[4];
    #pragma unroll
    for (int r = 0; r < 4; r++) invo[r] = __shfl(inv, (l & 48) | (lg*4 + r));
    #pragma unroll
    for (int c = 0; c < 16; c++)
      #pragma unroll
      for (int r = 0; r < 4; r++){
        int n = n0 + w*32 + qt*16 + lg*4 + r;
        Op[((size_t)part*BN_ + (size_t)b*N_ + n)*C_ + c*16 + lq] = f2bf(oacc[qt][c][r]*invo[r]);
      }
    if (lg == 0){
      int n = n0 + w*32 + qt*16 + lq;
      Mp[part*BN_ + b*N_ + n] = m[qt];
      Lp[part*BN_ + b*N_ + n] = lsum[qt];
    }
  }
}

// ---------------- K4b: combine 4 KV quarters ----------------
__global__ __launch_bounds__(256) void k_comb4(const short* __restrict__ Op, const float* __restrict__ Mp,
    const float* __restrict__ Lp, short* __restrict__ Xa){
  int tid = threadIdx.x;
  int rg = blockIdx.x*8 + (tid>>5);
  int cc = (tid&31)*8;
  float mv[4], lv[4];
  float m = -1e30f;
  #pragma unroll
  for (int p = 0; p < 4; p++){ mv[p] = Mp[p*BN_ + rg]; lv[p] = Lp[p*BN_ + rg]; m = fmaxf(m, mv[p]); }
  float wgt[4], wsum = 0.f;
  #pragma unroll
  for (int p = 0; p < 4; p++){ wgt[p] = lv[p]*__expf(mv[p]-m); wsum += wgt[p]; }
  float inv = 1.f/wsum;
  float acc[8];
  #pragma unroll
  for (int j = 0; j < 8; j++) acc[j] = 0.f;
  #pragma unroll
  for (int p = 0; p < 4; p++){
    bf16x8 o = *(const bf16x8*)(Op + ((size_t)p*BN_ + rg)*C_ + cc);
    #pragma unroll
    for (int j = 0; j < 8; j++) acc[j] += wgt[p]*bf2f(o[j]);
  }
  bf16x8 r;
  #pragma unroll
  for (int j = 0; j < 8; j++) r[j] = f2bf(acc[j]*inv);
  *(bf16x8*)(Xa + (size_t)rg*C_ + cc) = r;
}

// ---------------- K4 fallback (R4-proven): 2-way split, dbuf K+V in LDS ----------------
__global__ __launch_bounds__(512) void k_attn2(const short* __restrict__ Q, const short* __restrict__ K,
    const short* __restrict__ Vt, short* __restrict__ Op, float* __restrict__ Mp, float* __restrict__ Lp){
  extern __shared__ short smem[];
  short* Ks = smem;
  short* Vs = smem + 32768;
  int bid = blockIdx.x;
  int xcd = bid & 7;
  int b = xcd >> 1;
  int half = xcd & 1;
  int n0 = (bid >> 3) * 128;
  int kv0 = half * 2048;
  int tid = threadIdx.x, w = tid>>6, l = tid&63, lq = l&15, lg = l>>4;
  const short* Qb = Q + (size_t)b*N_*C_;
  const short* Kb = K + (size_t)b*N_*C_;
  const short* Vb = Vt + (size_t)b*C_*N_;
  short* lp = smem + 65536 + w*(16*72);
  int krow0 = w*8 + (l>>5);
  int kchunk0 = l&31;
  int vrow0 = w*32 + (l>>3);
  int vchunk = (l&7) ^ ((l>>3)&7);
  bf16x8 qf[8];
  {
    const short* qrow = Qb + (size_t)(n0 + w*16 + lq)*C_ + lg*8;
    #pragma unroll
    for (int kk = 0; kk < 8; kk++) qf[kk] = *(const bf16x8*)(qrow + kk*32);
  }
  f32x4 zero = {0.f,0.f,0.f,0.f};
  f32x4 oacc[16];
  #pragma unroll
  for (int c = 0; c < 16; c++) oacc[c] = zero;
  float mrow[4], lsum[4];
  #pragma unroll
  for (int r = 0; r < 4; r++){ mrow[r] = -1e30f; lsum[r] = 0.f; }
  int swz = lq & 7;
  auto stage = [&](int buf, int m0){
    short* kd = Ks + buf*16384 + w*2048;
    short* vd = Vs + buf*16384 + w*2048;
    #pragma unroll
    for (int i = 0; i < 4; i++){
      int row = krow0 + i*2;
      int chunk = kchunk0 ^ (row & 7);
      gload_lds16(Kb + (size_t)(m0 + row)*C_ + chunk*8, kd + i*512);
    }
    #pragma unroll
    for (int i = 0; i < 4; i++){
      int row = vrow0 + i*8;
      gload_lds16(Vb + (size_t)row*N_ + m0 + vchunk*8, vd + i*512);
    }
  };
  stage(0, kv0);
  __syncthreads();
  int cur = 0;
  for (int mt = 0; mt < 32; mt++){
    if (mt + 1 < 32) stage(cur^1, kv0 + (mt+1)*64);
    const short* Kc = Ks + cur*16384;
    const short* Vc = Vs + cur*16384;
    f32x4 sa[4];
    #pragma unroll
    for (int s = 0; s < 4; s++) sa[s] = zero;
    __builtin_amdgcn_s_setprio(1);
    #pragma unroll
    for (int s = 0; s < 4; s++){
      const short* krowp = Kc + (s*16 + lq)*256;
      #pragma unroll
      for (int kk = 0; kk < 8; kk++){
        bf16x8 kf = *(const bf16x8*)(krowp + (((kk*4 + lg) ^ swz) << 3));
        sa[s] = __builtin_amdgcn_mfma_f32_16x16x32_bf16(qf[kk], kf, sa[s], 0, 0, 0);
      }
    }
    __builtin_amdgcn_s_setprio(0);
    float tmax[4];
    #pragma unroll
    for (int r = 0; r < 4; r++){
      float t = fmaxf(fmaxf(sa[0][r], sa[1][r]), fmaxf(sa[2][r], sa[3][r]));
      t = fmaxf(t, __shfl_xor(t, 1));
      t = fmaxf(t, __shfl_xor(t, 2));
      t = fmaxf(t, __shfl_xor(t, 4));
      t = fmaxf(t, __shfl_xor(t, 8));
      tmax[r] = t;
    }
    bool need = (tmax[0] > mrow[0]+8.f) | (tmax[1] > mrow[1]+8.f) |
                (tmax[2] > mrow[2]+8.f) | (tmax[3] > mrow[3]+8.f);
    if (__any(need)){
      float al[4];
      #pragma unroll
      for (int r = 0; r < 4; r++){
        float mn = fmaxf(mrow[r], tmax[r]);
        al[r] = __expf(mrow[r] - mn);
        mrow[r] = mn;
        lsum[r] *= al[r];
      }
      #pragma unroll
      for (int c = 0; c < 16; c++){
        f32x4 o = oacc[c];
        o[0]*=al[0]; o[1]*=al[1]; o[2]*=al[2]; o[3]*=al[3];
        oacc[c] = o;
      }
    }
    #pragma unroll
    for (int s = 0; s < 4; s++)
      #pragma unroll
      for (int r = 0; r < 4; r++)
        sa[s][r] = __expf(sa[s][r] - mrow[r]);
    #pragma unroll
    for (int r = 0; r < 4; r++){
      float t = sa[0][r] + sa[1][r] + sa[2][r] + sa[3][r];
      t += __shfl_xor(t, 1); t += __shfl_xor(t, 2);
      t += __shfl_xor(t, 4); t += __shfl_xor(t, 8);
      lsum[r] += t;
    }
    #pragma unroll
    for (int s = 0; s < 4; s++)
      #pragma unroll
      for (int r = 0; r < 4; r++)
        lp[(lg*4 + r)*72 + s*16 + lq] = f2bf(sa[s][r]);
    __builtin_amdgcn_sched_barrier(0);
    __builtin_amdgcn_s_setprio(1);
    #pragma unroll
    for (int s2 = 0; s2 < 2; s2++){
      bf16x8 pa = *(const bf16x8*)(lp + lq*72 + s2*32 + lg*8);
      #pragma unroll
      for (int c = 0; c < 16; c++){
        bf16x8 vbf = *(const bf16x8*)(Vc + (c*16 + lq)*64 + (((s2*4 + lg) ^ swz) << 3));
        oacc[c] = __builtin_amdgcn_mfma_f32_16x16x32_bf16(pa, vbf, oacc[c], 0, 0, 0);
      }
    }
    __builtin_amdgcn_s_setprio(0);
    __builtin_amdgcn_sched_barrier(0);
    __syncthreads();
    cur ^= 1;
  }
  float inv[4];
  #pragma unroll
  for (int r = 0; r < 4; r++) inv[r] = 1.f / lsum[r];
  #pragma unroll
  for (int c = 0; c < 16; c++)
    #pragma unroll
    for (int r = 0; r < 4; r++){
      int n = n0 + w*16 + lg*4 + r;
      Op[((size_t)half*BN_ + (size_t)b*N_ + n)*C_ + c*16 + lq] = f2bf(oacc[c][r]*inv[r]);
    }
  if (lq == 0){
    #pragma unroll
    for (int r = 0; r < 4; r++){
      int n = n0 + w*16 + lg*4 + r;
      Mp[half*BN_ + b*N_ + n] = mrow[r];
      Lp[half*BN_ + b*N_ + n] = lsum[r];
    }
  }
}

__global__ __launch_bounds__(256) void k_comb2(const short* __restrict__ Op, const float* __restrict__ Mp,
    const float* __restrict__ Lp, short* __restrict__ Xa){
  int tid = threadIdx.x;
  int rg = blockIdx.x*8 + (tid>>5);
  int cc = (tid&31)*8;
  float m1 = Mp[rg], m2 = Mp[BN_ + rg];
  float l1 = Lp[rg], l2 = Lp[BN_ + rg];
  float m = fmaxf(m1, m2);
  float w1 = l1 * __expf(m1 - m);
  float w2 = l2 * __expf(m2 - m);
  float inv = 1.f/(w1 + w2);
  w1 *= inv; w2 *= inv;
  bf16x8 o1 = *(const bf16x8*)(Op + (size_t)rg*C_ + cc);
  bf16x8 o2 = *(const bf16x8*)(Op + ((size_t)BN_ + rg)*C_ + cc);
  bf16x8 r;
  #pragma unroll
  for (int j = 0; j < 8; j++){
    float f = w1*bf2f(o1[j]) + w2*bf2f(o2[j]);
    r[j] = f2bf(f);
  }
  *(bf16x8*)(Xa + (size_t)rg*C_ + cc) = r;
}

// ---------------- K5: out = x + cplx * (wproj @ x_attn^T), 1024 blocks ----------------
__global__ __launch_bounds__(256) void k_proj(const float* __restrict__ x, const short* __restrict__ wpb,
    const short* __restrict__ Xa, const float* __restrict__ cplx, float* __restrict__ out){
  int b = blockIdx.z, o0 = blockIdx.y*64, n0 = blockIdx.x*64;
  int tid = threadIdx.x, w = tid>>6, l = tid&63, lq = l&15, lg = l>>4;
  f32x4 zero = {0.f,0.f,0.f,0.f};
  f32x4 acc[4];
  #pragma unroll
  for (int s = 0; s < 4; s++) acc[s] = zero;
  int orow = o0 + w*16 + lq;
  for (int kk = 0; kk < 8; kk++){
    int c0 = kk*32 + lg*8;
    bf16x8 aw = *(const bf16x8*)(wpb + orow*C_ + c0);
    #pragma unroll
    for (int s = 0; s < 4; s++){
      bf16x8 xb = *(const bf16x8*)(Xa + ((size_t)b*N_ + n0 + s*16 + lq)*C_ + c0);
      acc[s] = __builtin_amdgcn_mfma_f32_16x16x32_bf16(aw, xb, acc[s], 0, 0, 0);
    }
  }
  float cp = cplx[b];
  #pragma unroll
  for (int s = 0; s < 4; s++)
    #pragma unroll
    for (int r = 0; r < 4; r++){
      int o = o0 + w*16 + lg*4 + r;
      int n = n0 + s*16 + lq;
      size_t idx = ((size_t)b*C_ + o)*N_ + n;
      out[idx] = x[idx] + cp*acc[s][r];
    }
}

extern "C" void kernel_launch(void* const* d_in, const int* in_sizes, int n_in,
                              void* d_out, int out_size, void* d_ws, size_t ws_size,
                              hipStream_t stream){
  const float* x     = (const float*)d_in[0];
  const float* w_ce1 = (const float*)d_in[1];
  const float* w_ce2 = (const float*)d_in[2];
  const float* wq    = (const float*)d_in[3];
  const float* wk    = (const float*)d_in[4];
  const float* wv    = (const float*)d_in[5];
  const float* wproj = (const float*)d_in[6];
  float* out = (float*)d_out;

  const size_t mat = (size_t)B_*N_*C_;
  const size_t needA = (3*mat + 4*mat + 4*(size_t)C_*C_)*2 + (8*(size_t)BN_ + B_*C_ + 16)*4;
  bool use4 = ws_size >= needA;
  int nparts = use4 ? 4 : 2;

  char* p = (char*)d_ws;
  short* Q   = (short*)p;            p += mat*2;
  short* K   = (short*)p;            p += mat*2;
  short* Vt  = (short*)p;            p += mat*2;
  short* Op  = (short*)p;            p += (size_t)nparts*mat*2;
  float* Mp  = (float*)p;            p += (size_t)nparts*BN_*4;
  float* Lp  = (float*)p;            p += (size_t)nparts*BN_*4;
  float* feat= (float*)p;            p += B_*C_*4;
  float* cplx= (float*)p;            p += 64;
  short* wqb = (short*)p;            p += (size_t)C_*C_*2;
  short* wkb = (short*)p;            p += (size_t)C_*C_*2;
  short* wvb = (short*)p;            p += (size_t)C_*C_*2;
  short* wpb = (short*)p;
  short* Xa  = Q; // alias: Q dead after k_attn

  const int SMEM_A4 = 65536;                                  // 64 KiB dbuf (K+V, KVBLK=32)
  const int SMEM_A2 = (16384*2 + 16384*2 + 8*16*72) * 2;      // 149504
  hipFuncSetAttribute((const void*)k_attn4, hipFuncAttributeMaxDynamicSharedMemorySize, SMEM_A4);
  hipFuncSetAttribute((const void*)k_attn2, hipFuncAttributeMaxDynamicSharedMemorySize, SMEM_A2);

  hipLaunchKernelGGL(k_feat, dim3(B_*C_), dim3(256), 0, stream, x, feat);
  hipLaunchKernelGGL(k_cplx, dim3(B_), dim3(64), 0, stream, feat, w_ce1, w_ce2, cplx);
  hipLaunchKernelGGL(k_wcvt, dim3(256), dim3(256), 0, stream, wq, wk, wv, wproj, wqb, wkb, wvb, wpb);
  hipLaunchKernelGGL(k_qkv, dim3(64,4,4), dim3(256), 0, stream, x, wqb, wkb, wvb, Q, K, Vt);
  if (use4){
    hipLaunchKernelGGL(k_attn4, dim3(256), dim3(512), SMEM_A4, stream, Q, K, Vt, Op, Mp, Lp);
    hipLaunchKernelGGL(k_comb4, dim3(BN_/8), dim3(256), 0, stream, Op, Mp, Lp, Xa);
  } else {
    hipLaunchKernelGGL(k_attn2, dim3(256), dim3(512), SMEM_A2, stream, Q, K, Vt, Op, Mp, Lp);
    hipLaunchKernelGGL(k_comb2, dim3(BN_/8), dim3(256), 0, stream, Op, Mp, Lp, Xa);
  }
  hipLaunchKernelGGL(k_proj, dim3(64,4,4), dim3(256), 0, stream, x, wpb, Xa, cplx, out);
}